// Round 7
// baseline (232.449 us; speedup 1.0000x reference)
//
#include <hip/hip_runtime.h>
#include <cstdint>
#include <cstddef>

#define NB 2
#define SEQ 2048
#define DMODEL 2048
#define NHEAD 16
#define HDIM 128
#define NGRP 4
#define NKV (NGRP * HDIM)          // 512
#define NQKV (DMODEL + 2 * NKV)    // 3072
#define MROWS (NB * SEQ)           // 4096
// 1/sqrt(128) * log2(e): Q pre-scale so softmax uses exp2 directly
#define QSCALE_LOG2E 0.12751743f

typedef unsigned short u16_t;
typedef unsigned int u32_t;
typedef __bf16 bf16x8 __attribute__((ext_vector_type(8)));
typedef __bf16 bf16x4 __attribute__((ext_vector_type(4)));
typedef float f32x4 __attribute__((ext_vector_type(4)));

static __device__ __forceinline__ u16_t f2bf(float f) {
  u32_t u = __builtin_bit_cast(u32_t, f);
  u32_t r = u + 0x7FFFu + ((u >> 16) & 1u);
  return (u16_t)(r >> 16);
}

// ---------------- prep kernels ----------------

__global__ void k_cast_x(const float* __restrict__ x, u16_t* __restrict__ xb) {
  int i = blockIdx.x * 256 + threadIdx.x;          // group of 4 floats
  float4 v = ((const float4*)x)[i];
  uint2 pk;
  pk.x = (u32_t)f2bf(v.x) | ((u32_t)f2bf(v.y) << 16);
  pk.y = (u32_t)f2bf(v.z) | ((u32_t)f2bf(v.w) << 16);
  ((uint2*)xb)[i] = pk;
}

__global__ void k_tables(const float* __restrict__ rf, float* __restrict__ cosT,
                         float* __restrict__ sinT) {
  int i = blockIdx.x * 256 + threadIdx.x;          // < SEQ*HDIM/2
  float f = rf[i];
  cosT[i] = cosf(f);
  sinT[i] = sinf(f);
}

__global__ void k_bias(const float* __restrict__ bq, const float* __restrict__ bk,
                       const float* __restrict__ bv, float* __restrict__ bqkv) {
  int i = blockIdx.x * 256 + threadIdx.x;          // < NQKV
  float v = (i < DMODEL) ? bq[i] : (i < DMODEL + NKV ? bk[i - DMODEL] : bv[i - DMODEL - NKV]);
  bqkv[i] = v;
}

// W: [K][N] fp32 row-major -> Wt: [N][K] bf16 row-major
__global__ void k_transpose_cast(const float* __restrict__ W, int N,
                                 u16_t* __restrict__ Wt, int K) {
  __shared__ float tile[64][65];
  int n0 = blockIdx.x * 64, k0 = blockIdx.y * 64;
  int t = threadIdx.x;
#pragma unroll
  for (int pass = 0; pass < 4; ++pass) {
    int slot = pass * 256 + t;
    int r = slot >> 4, c4 = (slot & 15) * 4;
    float4 v = *(const float4*)(W + (size_t)(k0 + r) * N + n0 + c4);
    tile[r][c4] = v.x; tile[r][c4 + 1] = v.y; tile[r][c4 + 2] = v.z; tile[r][c4 + 3] = v.w;
  }
  __syncthreads();
  int nr = t >> 2, seg = t & 3;
  alignas(16) u16_t o[16];
#pragma unroll
  for (int kk = 0; kk < 16; ++kk) o[kk] = f2bf(tile[seg * 16 + kk][nr]);
  u16_t* dst = Wt + (size_t)(n0 + nr) * K + k0 + seg * 16;
  ((int4*)dst)[0] = ((const int4*)o)[0];
  ((int4*)dst)[1] = ((const int4*)o)[1];
}

// ---------------- GEMM: C[M][N] = A[M][K](bf16) * Bt[N][K](bf16)^T + bias ----------
// 256x256 tile, BK=64, 512 threads (8 waves: wr=wid>>2 in 2, wc=wid&3 in 4),
// per-wave output 128x64 (acc[8][4] 16x16 frags). Double-buffered LDS (128KB),
// counted vmcnt(8) (tile t waited, tile t+1 in flight), raw barriers, XOR-swizzled
// reads (stage pre-swizzles the GLOBAL source; LDS dest stays linear), setprio
// around MFMA clusters, m204-bijective XCD-aware block swizzle.
// EPI 0: fp32 out.  EPI 1: QKV epilogue (RoPE on Q/K, Q pre-scaled, V transposed).

template <int EPI>
__global__ __launch_bounds__(512, 2) void k_gemm(
    const u16_t* __restrict__ A, const u16_t* __restrict__ Bt, const float* __restrict__ bias,
    float* __restrict__ Cout, u16_t* __restrict__ Qb, u16_t* __restrict__ Kb,
    u16_t* __restrict__ Vt, const float* __restrict__ cosT, const float* __restrict__ sinT,
    int M, int N, int K) {
  // [0..32767] A slots 0,1 ([256][64] each); [32768..65535] B slots 0,1.
  __shared__ u16_t lds[65536];

  int tid = threadIdx.x;
  int wid = tid >> 6, lane = tid & 63;
  int l15 = lane & 15, l4 = lane >> 4;
  int wr = wid >> 2, wc = wid & 3;

  // m204 bijective XCD swizzle on a 1D grid
  int nwg = gridDim.x, lin = blockIdx.x;
  int qq = nwg >> 3, rr8 = nwg & 7;
  int xcd = lin & 7, idx = lin >> 3;
  int wgid = (xcd < rr8 ? xcd * (qq + 1) : rr8 * (qq + 1) + (xcd - rr8) * qq) + idx;
  int nxt = N >> 8;
  int by = wgid / nxt, bx = wgid - by * nxt;
  int m0 = by << 8, n0 = bx << 8;

  f32x4 acc[8][4] = {};

  // stage K-tile t into slot (t&1). A [256][64], B [256][64]; source col-chunk
  // pre-swizzled c' = c ^ (row&7) so swizzled ds_reads see linear data.
  auto stage = [&](int t) {
    u16_t* Al = lds + (t & 1) * 16384;
    u16_t* Bl = lds + 32768 + (t & 1) * 16384;
    int kbase = t * 64;
#pragma unroll
    for (int rd = 0; rd < 4; ++rd) {
      int slot = tid + rd * 512;
      int r = slot >> 3, c = slot & 7;
      int cs = c ^ (r & 7);
      __builtin_amdgcn_global_load_lds(
          (const __attribute__((address_space(1))) u32_t*)(A + (size_t)(m0 + r) * K + kbase + cs * 8),
          (__attribute__((address_space(3))) u32_t*)(Al + slot * 8), 16, 0, 0);
    }
#pragma unroll
    for (int rd = 0; rd < 4; ++rd) {
      int slot = tid + rd * 512;
      int r = slot >> 3, c = slot & 7;
      int cs = c ^ (r & 7);
      __builtin_amdgcn_global_load_lds(
          (const __attribute__((address_space(1))) u32_t*)(Bt + (size_t)(n0 + r) * K + kbase + cs * 8),
          (__attribute__((address_space(3))) u32_t*)(Bl + slot * 8), 16, 0, 0);
    }
  };

  stage(0);
  stage(1);

  const int NT = K >> 6;   // 32
  for (int t = 0; t < NT; ++t) {
    if (t == NT - 1) {
      asm volatile("s_waitcnt vmcnt(0)" ::: "memory");
    } else {
      asm volatile("s_waitcnt vmcnt(8)" ::: "memory");   // tile t landed; t+1 in flight
    }
    __builtin_amdgcn_s_barrier();                        // #1: slot (t&1) valid
    __builtin_amdgcn_sched_barrier(0);

    const u16_t* Acur = lds + (t & 1) * 16384;
    const u16_t* Bcur = lds + 32768 + (t & 1) * 16384;

#pragma unroll
    for (int kk = 0; kk < 2; ++kk) {
      bf16x8 bfr[4];
#pragma unroll
      for (int n = 0; n < 4; ++n) {
        int row = wc * 64 + n * 16 + l15;
        int chunk = ((kk << 2) + l4) ^ (l15 & 7);
        bfr[n] = *(const bf16x8*)(Bcur + row * 64 + chunk * 8);
      }
#pragma unroll
      for (int mh = 0; mh < 2; ++mh) {
        bf16x8 afr[4];
#pragma unroll
        for (int mi = 0; mi < 4; ++mi) {
          int row = wr * 128 + (mh * 4 + mi) * 16 + l15;
          int chunk = ((kk << 2) + l4) ^ (l15 & 7);
          afr[mi] = *(const bf16x8*)(Acur + row * 64 + chunk * 8);
        }
        __builtin_amdgcn_s_setprio(1);
#pragma unroll
        for (int mi = 0; mi < 4; ++mi)
#pragma unroll
          for (int n = 0; n < 4; ++n)
            acc[mh * 4 + mi][n] =
                __builtin_amdgcn_mfma_f32_16x16x32_bf16(afr[mi], bfr[n], acc[mh * 4 + mi][n], 0, 0, 0);
        __builtin_amdgcn_s_setprio(0);
      }
    }

    __builtin_amdgcn_sched_barrier(0);
    __builtin_amdgcn_s_barrier();                        // #2: slot (t&1) free
    __builtin_amdgcn_sched_barrier(0);
    if (t + 2 < NT) stage(t + 2);                        // into slot (t&1)
  }

  // ---------------- epilogue ----------------
  if (EPI == 0) {
#pragma unroll
    for (int n = 0; n < 4; ++n) {
      int col = n0 + wc * 64 + n * 16 + l15;
      float bs = bias[col];
#pragma unroll
      for (int m = 0; m < 8; ++m) {
        int mbase = m0 + wr * 128 + m * 16 + l4 * 4;
#pragma unroll
        for (int r = 0; r < 4; ++r)
          Cout[(size_t)(mbase + r) * N + col] = acc[m][n][r] + bs;
      }
    }
  } else {
    bool isV = (n0 >= DMODEL + NKV);
    bool isK = (n0 >= DMODEL) && !isV;
#pragma unroll
    for (int n = 0; n < 4; ++n) {
      int col = n0 + wc * 64 + n * 16 + l15;
      float bs = bias[col];
      int d = col & (HDIM - 1);
      int p = d >> 1;
      bool evn = !(d & 1);
#pragma unroll
      for (int m = 0; m < 8; ++m) {
        int mbase = m0 + wr * 128 + m * 16 + l4 * 4;
        if (isV) {
          int g = (col - DMODEL - NKV) >> 7;
          int b = mbase >> 11, s0 = mbase & (SEQ - 1);
          u16_t o[4];
#pragma unroll
          for (int r = 0; r < 4; ++r) o[r] = f2bf(acc[m][n][r] + bs);
          uint2 pk;
          pk.x = (u32_t)o[0] | ((u32_t)o[1] << 16);
          pk.y = (u32_t)o[2] | ((u32_t)o[3] << 16);
          *(uint2*)(Vt + ((size_t)(b * NGRP + g) * HDIM + d) * SEQ + s0) = pk;
        } else {
#pragma unroll
          for (int r = 0; r < 4; ++r) {
            int mrow = mbase + r;
            int b = mrow >> 11, s = mrow & (SEQ - 1);
            float val = acc[m][n][r] + bs;
            float pv = __shfl_xor(val, 1);
            float c = cosT[s * (HDIM / 2) + p];
            float sn = sinT[s * (HDIM / 2) + p];
            float outv = evn ? (val * c - pv * sn) : (pv * sn + val * c);
            if (isK) {
              int g = (col - DMODEL) >> 7;
              Kb[((size_t)(b * NGRP + g) * SEQ + s) * HDIM + d] = f2bf(outv);
            } else {
              int h = col >> 7;
              Qb[((size_t)(b * NHEAD + h) * SEQ + s) * HDIM + d] = f2bf(outv * QSCALE_LOG2E);
            }
          }
        }
      }
    }
  }
}

// ---------------- flash attention (unchanged from round 6) ----------------

__global__ __launch_bounds__(256) void k_attn(
    const u16_t* __restrict__ Qb, const u16_t* __restrict__ Kb, const u16_t* __restrict__ Vt,
    u16_t* __restrict__ attn_out) {
  __shared__ u16_t lds[32768];

  int tid = threadIdx.x, wid = tid >> 6, lane = tid & 63;
  int l15 = lane & 15, l4 = lane >> 4;
  int bh = blockIdx.y;
  int b = bh >> 4, h = bh & 15, g = h >> 2;
  int q0 = blockIdx.x * 128;
  const u16_t* Qhead = Qb + (size_t)(b * NHEAD + h) * SEQ * HDIM;
  const u16_t* Khead = Kb + (size_t)(b * NGRP + g) * SEQ * HDIM;
  const u16_t* Vhead = Vt + (size_t)(b * NGRP + g) * HDIM * SEQ;

  bf16x8 qfa[4], qfb[4];
#pragma unroll
  for (int kc = 0; kc < 4; ++kc) {
    qfa[kc] = *(const bf16x8*)(Qhead + (size_t)(q0 + wid * 32 + l15) * HDIM + kc * 32 + l4 * 8);
    qfb[kc] = *(const bf16x8*)(Qhead + (size_t)(q0 + wid * 32 + 16 + l15) * HDIM + kc * 32 + l4 * 8);
  }

  f32x4 oa[8] = {}, ob[8] = {};
  float la = 0.f, lb = 0.f;

  auto stage = [&](int kv0, int bufIdx) {
    u16_t* Kl = lds + bufIdx * 8192;
    u16_t* Vl = lds + 16384 + bufIdx * 8192;
#pragma unroll
    for (int ss = 0; ss < 4; ++ss) {
      int slot = tid + ss * 256;
      int rK = slot >> 4;
      int cK = (slot & 15) ^ ((rK & 3) | (((rK >> 3) & 1) << 2));
      __builtin_amdgcn_global_load_lds(
          (const __attribute__((address_space(1))) u32_t*)(Khead + (size_t)(kv0 + rK) * HDIM + cK * 8),
          (__attribute__((address_space(3))) u32_t*)(Kl + slot * 8), 16, 0, 0);
      int rV = slot >> 3, cV = (slot & 7) ^ (rV & 7);
      __builtin_amdgcn_global_load_lds(
          (const __attribute__((address_space(1))) u32_t*)(Vhead + (size_t)rV * SEQ + kv0 + cV * 8),
          (__attribute__((address_space(3))) u32_t*)(Vl + slot * 8), 16, 0, 0);
    }
  };

  stage(0, 0);

  const int NT = SEQ / 64;
  for (int t = 0; t < NT; ++t) {
    int cur = t & 1;
    if (t + 1 < NT) {
      stage((t + 1) * 64, cur ^ 1);
      asm volatile("s_waitcnt vmcnt(8)" ::: "memory");
    } else {
      asm volatile("s_waitcnt vmcnt(0)" ::: "memory");
    }
    __builtin_amdgcn_s_barrier();
    __builtin_amdgcn_sched_barrier(0);

    const u16_t* Kcur = lds + cur * 8192;
    const u16_t* Vcur = lds + 16384 + cur * 8192;

    f32x4 sa[4] = {}, sb[4] = {};
    __builtin_amdgcn_s_setprio(1);
#pragma unroll
    for (int kc = 0; kc < 4; ++kc) {
#pragma unroll
      for (int kvb = 0; kvb < 4; ++kvb) {
        int row = (l15 >> 2) * 8 + ((kvb & 1) << 2) + (l15 & 3) + ((kvb >> 1) << 5);
        int chunk = ((kc << 2) + l4) ^ (l15 & 7);
        bf16x8 kf = *(const bf16x8*)(Kcur + row * 128 + chunk * 8);
        sa[kvb] = __builtin_amdgcn_mfma_f32_16x16x32_bf16(kf, qfa[kc], sa[kvb], 0, 0, 0);
        sb[kvb] = __builtin_amdgcn_mfma_f32_16x16x32_bf16(kf, qfb[kc], sb[kvb], 0, 0, 0);
      }
    }
    __builtin_amdgcn_s_setprio(0);

    bf16x4 pa[4], pb[4];
#pragma unroll
    for (int kvb = 0; kvb < 4; ++kvb) {
#pragma unroll
      for (int r = 0; r < 4; ++r) {
        float ea = __builtin_amdgcn_exp2f(sa[kvb][r]);
        float eb = __builtin_amdgcn_exp2f(sb[kvb][r]);
        la += ea; lb += eb;
        pa[kvb][r] = (__bf16)ea;
        pb[kvb][r] = (__bf16)eb;
      }
    }

    bf16x8 pfa[2], pfb[2];
#pragma unroll
    for (int kc2 = 0; kc2 < 2; ++kc2) {
      uint2 alo = __builtin_bit_cast(uint2, pa[kc2 * 2]);
      uint2 ahi = __builtin_bit_cast(uint2, pa[kc2 * 2 + 1]);
      uint4 wa; wa.x = alo.x; wa.y = alo.y; wa.z = ahi.x; wa.w = ahi.y;
      pfa[kc2] = __builtin_bit_cast(bf16x8, wa);
      uint2 blo = __builtin_bit_cast(uint2, pb[kc2 * 2]);
      uint2 bhi = __builtin_bit_cast(uint2, pb[kc2 * 2 + 1]);
      uint4 wb; wb.x = blo.x; wb.y = blo.y; wb.z = bhi.x; wb.w = bhi.y;
      pfb[kc2] = __builtin_bit_cast(bf16x8, wb);
    }

    __builtin_amdgcn_s_setprio(1);
#pragma unroll
    for (int kc2 = 0; kc2 < 2; ++kc2) {
#pragma unroll
      for (int dcb = 0; dcb < 8; ++dcb) {
        int chunk = ((kc2 << 2) + l4) ^ (l15 & 7);
        bf16x8 vf = *(const bf16x8*)(Vcur + (dcb * 16 + l15) * 64 + chunk * 8);
        oa[dcb] = __builtin_amdgcn_mfma_f32_16x16x32_bf16(vf, pfa[kc2], oa[dcb], 0, 0, 0);
        ob[dcb] = __builtin_amdgcn_mfma_f32_16x16x32_bf16(vf, pfb[kc2], ob[dcb], 0, 0, 0);
      }
    }
    __builtin_amdgcn_s_setprio(0);

    __builtin_amdgcn_sched_barrier(0);
    __builtin_amdgcn_s_barrier();
  }

  la += __shfl_xor(la, 16); la += __shfl_xor(la, 32);
  lb += __shfl_xor(lb, 16); lb += __shfl_xor(lb, 32);
  float inva = 1.0f / la, invb = 1.0f / lb;

#pragma unroll
  for (int half = 0; half < 2; ++half) {
    u16_t* Owave = lds + half * 8704 + wid * 2176;
    const f32x4* oacc = half ? ob : oa;
    float inv = half ? invb : inva;
#pragma unroll
    for (int dcb = 0; dcb < 8; ++dcb) {
      bf16x4 ov;
#pragma unroll
      for (int r = 0; r < 4; ++r) ov[r] = (__bf16)(oacc[dcb][r] * inv);
      *(uint2*)(Owave + l15 * 136 + dcb * 16 + l4 * 4) = __builtin_bit_cast(uint2, ov);
    }
#pragma unroll
    for (int pass = 0; pass < 4; ++pass) {
      int rowq = pass * 4 + l4;
      int4 v = *(const int4*)(Owave + rowq * 136 + l15 * 8);
      int s = q0 + wid * 32 + half * 16 + rowq;
      *(int4*)(attn_out + ((size_t)(b * SEQ + s)) * DMODEL + h * HDIM + l15 * 8) = v;
    }
  }
}

// ---------------- launcher ----------------

extern "C" void kernel_launch(void* const* d_in, const int* in_sizes, int n_in,
                              void* d_out, int out_size, void* d_ws, size_t ws_size,
                              hipStream_t stream) {
  (void)in_sizes; (void)n_in; (void)out_size; (void)ws_size;
  const float* x  = (const float*)d_in[0];
  const float* rf = (const float*)d_in[1];
  const float* Wq = (const float*)d_in[2];
  const float* bq = (const float*)d_in[3];
  const float* Wk = (const float*)d_in[4];
  const float* bk = (const float*)d_in[5];
  const float* Wv = (const float*)d_in[6];
  const float* bv = (const float*)d_in[7];
  const float* Wo = (const float*)d_in[8];
  const float* bo = (const float*)d_in[9];
  float* out = (float*)d_out;

  char* ws = (char*)d_ws;
  u16_t* xb    = (u16_t*)ws;  ws += (size_t)MROWS * DMODEL * 2;
  u16_t* Wqkvt = (u16_t*)ws;  ws += (size_t)NQKV * DMODEL * 2;
  u16_t* Wot   = (u16_t*)ws;  ws += (size_t)DMODEL * DMODEL * 2;
  float* bqkv  = (float*)ws;  ws += (size_t)NQKV * 4;
  float* cosT  = (float*)ws;  ws += (size_t)SEQ * (HDIM / 2) * 4;
  float* sinT  = (float*)ws;  ws += (size_t)SEQ * (HDIM / 2) * 4;
  u16_t* Qb    = (u16_t*)ws;  ws += (size_t)NB * NHEAD * SEQ * HDIM * 2;
  u16_t* Kb    = (u16_t*)ws;  ws += (size_t)NB * NGRP * SEQ * HDIM * 2;
  u16_t* Vt    = (u16_t*)ws;  ws += (size_t)NB * NGRP * HDIM * SEQ * 2;
  u16_t* attn  = xb;  // alias: xb dead after GEMM1 (strict stream ordering)

  k_cast_x<<<MROWS * DMODEL / 1024, 256, 0, stream>>>(x, xb);
  k_tables<<<SEQ * (HDIM / 2) / 256, 256, 0, stream>>>(rf, cosT, sinT);
  k_bias<<<NQKV / 256, 256, 0, stream>>>(bq, bk, bv, bqkv);

  dim3 tgq(DMODEL / 64, DMODEL / 64);
  dim3 tgk(NKV / 64, DMODEL / 64);
  k_transpose_cast<<<tgq, 256, 0, stream>>>(Wq, DMODEL, Wqkvt, DMODEL);
  k_transpose_cast<<<tgk, 256, 0, stream>>>(Wk, NKV, Wqkvt + (size_t)DMODEL * DMODEL, DMODEL);
  k_transpose_cast<<<tgk, 256, 0, stream>>>(Wv, NKV, Wqkvt + (size_t)(DMODEL + NKV) * DMODEL, DMODEL);
  k_transpose_cast<<<tgq, 256, 0, stream>>>(Wo, DMODEL, Wot, DMODEL);

  // GEMM1: 4096 x 3072 x 2048 -> 16*12 = 192 blocks of 512 threads
  k_gemm<1><<<dim3((MROWS / 256) * (NQKV / 256)), 512, 0, stream>>>(
      xb, Wqkvt, bqkv, nullptr, Qb, Kb, Vt, cosT, sinT, MROWS, NQKV, DMODEL);

  dim3 ga(SEQ / 128, NB * NHEAD);
  k_attn<<<ga, 256, 0, stream>>>(Qb, Kb, Vt, attn);

  // GEMM2: 4096 x 2048 x 2048 -> 16*8 = 128 blocks
  k_gemm<0><<<dim3((MROWS / 256) * (DMODEL / 256)), 512, 0, stream>>>(
      attn, Wot, bo, out, nullptr, nullptr, nullptr, nullptr, nullptr, MROWS, DMODEL, DMODEL);
}

// Round 9
// 225.448 us; speedup vs baseline: 1.0311x; 1.0311x over previous
//
#include <hip/hip_runtime.h>
#include <cstdint>
#include <cstddef>

#define NB 2
#define SEQ 2048
#define DMODEL 2048
#define NHEAD 16
#define HDIM 128
#define NGRP 4
#define NKV (NGRP * HDIM)          // 512
#define NQKV (DMODEL + 2 * NKV)    // 3072
#define MROWS (NB * SEQ)           // 4096
// 1/sqrt(128) * log2(e): Q pre-scale so softmax uses exp2 directly
#define QSCALE_LOG2E 0.12751743f

typedef unsigned short u16_t;
typedef unsigned int u32_t;
typedef __bf16 bf16x8 __attribute__((ext_vector_type(8)));
typedef __bf16 bf16x4 __attribute__((ext_vector_type(4)));
typedef float f32x4 __attribute__((ext_vector_type(4)));

static __device__ __forceinline__ u16_t f2bf(float f) {
  u32_t u = __builtin_bit_cast(u32_t, f);
  u32_t r = u + 0x7FFFu + ((u >> 16) & 1u);
  return (u16_t)(r >> 16);
}

// ---------------- prep kernels ----------------

__global__ void k_cast_x(const float* __restrict__ x, u16_t* __restrict__ xb) {
  int i = blockIdx.x * 256 + threadIdx.x;          // group of 4 floats
  float4 v = ((const float4*)x)[i];
  uint2 pk;
  pk.x = (u32_t)f2bf(v.x) | ((u32_t)f2bf(v.y) << 16);
  pk.y = (u32_t)f2bf(v.z) | ((u32_t)f2bf(v.w) << 16);
  ((uint2*)xb)[i] = pk;
}

__global__ void k_tables(const float* __restrict__ rf, float* __restrict__ cosT,
                         float* __restrict__ sinT) {
  int i = blockIdx.x * 256 + threadIdx.x;          // < SEQ*HDIM/2
  float f = rf[i];
  cosT[i] = cosf(f);
  sinT[i] = sinf(f);
}

__global__ void k_bias(const float* __restrict__ bq, const float* __restrict__ bk,
                       const float* __restrict__ bv, float* __restrict__ bqkv) {
  int i = blockIdx.x * 256 + threadIdx.x;          // < NQKV
  float v = (i < DMODEL) ? bq[i] : (i < DMODEL + NKV ? bk[i - DMODEL] : bv[i - DMODEL - NKV]);
  bqkv[i] = v;
}

// W: [K][N] fp32 row-major -> Wt: [N][K] bf16 row-major
__global__ void k_transpose_cast(const float* __restrict__ W, int N,
                                 u16_t* __restrict__ Wt, int K) {
  __shared__ float tile[64][65];
  int n0 = blockIdx.x * 64, k0 = blockIdx.y * 64;
  int t = threadIdx.x;
#pragma unroll
  for (int pass = 0; pass < 4; ++pass) {
    int slot = pass * 256 + t;
    int r = slot >> 4, c4 = (slot & 15) * 4;
    float4 v = *(const float4*)(W + (size_t)(k0 + r) * N + n0 + c4);
    tile[r][c4] = v.x; tile[r][c4 + 1] = v.y; tile[r][c4 + 2] = v.z; tile[r][c4 + 3] = v.w;
  }
  __syncthreads();
  int nr = t >> 2, seg = t & 3;
  alignas(16) u16_t o[16];
#pragma unroll
  for (int kk = 0; kk < 16; ++kk) o[kk] = f2bf(tile[seg * 16 + kk][nr]);
  u16_t* dst = Wt + (size_t)(n0 + nr) * K + k0 + seg * 16;
  ((int4*)dst)[0] = ((const int4*)o)[0];
  ((int4*)dst)[1] = ((const int4*)o)[1];
}

// ---------------- GEMM: C[M][N] = A[M][K](bf16) * Bt[N][K](bf16)^T + bias ----------
// 128x128 tile, BK=32, 256 threads (4 waves, 2x2), per-wave 64x64 (acc[4][4]).
// Round-9: R8 geometry (fills 256 CUs) + R7's PROVEN two-barrier counted ledger:
//   prologue stage(0), stage(1)  [8 VMEM instr/wave in flight]
//   per tile t: vmcnt(4) (waits tile t, tile t+1 stays in flight; 0 on last)
//               -> s_barrier #1 -> compute(slot t&1) -> s_barrier #2
//               -> stage(t+2) into slot t&1
// Linear LDS (T2 null at 2-phase), setprio on MFMA cluster, column-major
// XCD stripes (T1). EPI 0: fp32 out. EPI 1: QKV epilogue (RoPE, V transposed).

template <int EPI>
__global__ __launch_bounds__(256, 2) void k_gemm(
    const u16_t* __restrict__ A, const u16_t* __restrict__ Bt, const float* __restrict__ bias,
    float* __restrict__ Cout, u16_t* __restrict__ Qb, u16_t* __restrict__ Kb,
    u16_t* __restrict__ Vt, const float* __restrict__ cosT, const float* __restrict__ sinT,
    int M, int N, int K) {
  // [0..8191] A slot0, [8192..16383] A slot1, [16384..] B slot0, B slot1 (u16)
  __shared__ u16_t lds[32768];
  int tid = threadIdx.x;
  int wid = tid >> 6, lane = tid & 63;
  int l15 = lane & 15, l4 = lane >> 4;
  int wrow = wid >> 1, wcol = wid & 1;

  // XCD-aware decode (grid divisible by 8): column-major per-XCD stripes
  int nwg = gridDim.x;
  int nby = M >> 7;
  int qq = nwg >> 3;
  int xcd = blockIdx.x & 7, idx = blockIdx.x >> 3;
  int wgid = xcd * qq + idx;
  int bx = wgid / nby, by = wgid - bx * nby;
  int m0 = by << 7, n0 = bx << 7;

  f32x4 acc[4][4] = {};

  // stage K-tile t into slot (t&1): A[128][32], B[128][32], linear.
  // 4 VMEM instructions per wave per stage.
  auto stage = [&](int t) {
    u16_t* Al = lds + (t & 1) * 8192;
    u16_t* Bl = lds + 16384 + (t & 1) * 8192;
    int kbase = t * 32;
#pragma unroll
    for (int ss = 0; ss < 2; ++ss) {
      int slot = tid + ss * 256;
      int row = slot >> 2, part = slot & 3;
      __builtin_amdgcn_global_load_lds(
          (const __attribute__((address_space(1))) u32_t*)(A + (size_t)(m0 + row) * K + kbase + part * 8),
          (__attribute__((address_space(3))) u32_t*)(Al + slot * 8), 16, 0, 0);
      __builtin_amdgcn_global_load_lds(
          (const __attribute__((address_space(1))) u32_t*)(Bt + (size_t)(n0 + row) * K + kbase + part * 8),
          (__attribute__((address_space(3))) u32_t*)(Bl + slot * 8), 16, 0, 0);
    }
  };

  stage(0);
  stage(1);

  const int NT = K >> 5;   // 64
  for (int t = 0; t < NT; ++t) {
    if (t == NT - 1) {
      asm volatile("s_waitcnt vmcnt(0)" ::: "memory");
    } else {
      asm volatile("s_waitcnt vmcnt(4)" ::: "memory");   // tile t landed; t+1 in flight
    }
    __builtin_amdgcn_s_barrier();                        // #1: slot (t&1) valid
    __builtin_amdgcn_sched_barrier(0);

    const u16_t* Acur = lds + (t & 1) * 8192;
    const u16_t* Bcur = lds + 16384 + (t & 1) * 8192;

    bf16x8 af[4], bfr[4];
#pragma unroll
    for (int i = 0; i < 4; ++i)
      af[i] = *(const bf16x8*)(Acur + (wrow * 64 + i * 16 + l15) * 32 + l4 * 8);
#pragma unroll
    for (int j = 0; j < 4; ++j)
      bfr[j] = *(const bf16x8*)(Bcur + (wcol * 64 + j * 16 + l15) * 32 + l4 * 8);

    __builtin_amdgcn_s_setprio(1);
#pragma unroll
    for (int i = 0; i < 4; ++i)
#pragma unroll
      for (int j = 0; j < 4; ++j)
        acc[i][j] = __builtin_amdgcn_mfma_f32_16x16x32_bf16(af[i], bfr[j], acc[i][j], 0, 0, 0);
    __builtin_amdgcn_s_setprio(0);

    __builtin_amdgcn_sched_barrier(0);
    __builtin_amdgcn_s_barrier();                        // #2: slot (t&1) free
    __builtin_amdgcn_sched_barrier(0);
    if (t + 2 < NT) stage(t + 2);                        // into slot (t&1)
  }

  if (EPI == 0) {
#pragma unroll
    for (int j = 0; j < 4; ++j) {
      int n = n0 + wcol * 64 + j * 16 + l15;
      float bs = bias[n];
#pragma unroll
      for (int i = 0; i < 4; ++i) {
        int mbase = m0 + wrow * 64 + i * 16 + l4 * 4;
#pragma unroll
        for (int r = 0; r < 4; ++r)
          Cout[(size_t)(mbase + r) * N + n] = acc[i][j][r] + bs;
      }
    }
  } else {
    bool isV = (n0 >= DMODEL + NKV);
    bool isK = (n0 >= DMODEL) && !isV;
#pragma unroll
    for (int j = 0; j < 4; ++j) {
      int n = n0 + wcol * 64 + j * 16 + l15;
      float bs = bias[n];
      int d = n & (HDIM - 1);
      int p = d >> 1;
      bool evn = !(d & 1);
#pragma unroll
      for (int i = 0; i < 4; ++i) {
        int mbase = m0 + wrow * 64 + i * 16 + l4 * 4;
        if (isV) {
          int g = (n - DMODEL - NKV) >> 7;
          int b = mbase >> 11, s0 = mbase & (SEQ - 1);
          u16_t o[4];
#pragma unroll
          for (int r = 0; r < 4; ++r) o[r] = f2bf(acc[i][j][r] + bs);
          uint2 pk;
          pk.x = (u32_t)o[0] | ((u32_t)o[1] << 16);
          pk.y = (u32_t)o[2] | ((u32_t)o[3] << 16);
          *(uint2*)(Vt + ((size_t)(b * NGRP + g) * HDIM + d) * SEQ + s0) = pk;
        } else {
#pragma unroll
          for (int r = 0; r < 4; ++r) {
            int m = mbase + r;
            int b = m >> 11, s = m & (SEQ - 1);
            float val = acc[i][j][r] + bs;
            float pv = __shfl_xor(val, 1);
            float c = cosT[s * (HDIM / 2) + p];
            float sn = sinT[s * (HDIM / 2) + p];
            float outv = evn ? (val * c - pv * sn) : (pv * sn + val * c);
            if (isK) {
              int g = (n - DMODEL) >> 7;
              Kb[((size_t)(b * NGRP + g) * SEQ + s) * HDIM + d] = f2bf(outv);
            } else {
              int h = n >> 7;
              Qb[((size_t)(b * NHEAD + h) * SEQ + s) * HDIM + d] = f2bf(outv * QSCALE_LOG2E);
            }
          }
        }
      }
    }
  }
}

// ---------------- flash attention (unchanged from round 6) ----------------

__global__ __launch_bounds__(256) void k_attn(
    const u16_t* __restrict__ Qb, const u16_t* __restrict__ Kb, const u16_t* __restrict__ Vt,
    u16_t* __restrict__ attn_out) {
  __shared__ u16_t lds[32768];

  int tid = threadIdx.x, wid = tid >> 6, lane = tid & 63;
  int l15 = lane & 15, l4 = lane >> 4;
  int bh = blockIdx.y;
  int b = bh >> 4, h = bh & 15, g = h >> 2;
  int q0 = blockIdx.x * 128;
  const u16_t* Qhead = Qb + (size_t)(b * NHEAD + h) * SEQ * HDIM;
  const u16_t* Khead = Kb + (size_t)(b * NGRP + g) * SEQ * HDIM;
  const u16_t* Vhead = Vt + (size_t)(b * NGRP + g) * HDIM * SEQ;

  bf16x8 qfa[4], qfb[4];
#pragma unroll
  for (int kc = 0; kc < 4; ++kc) {
    qfa[kc] = *(const bf16x8*)(Qhead + (size_t)(q0 + wid * 32 + l15) * HDIM + kc * 32 + l4 * 8);
    qfb[kc] = *(const bf16x8*)(Qhead + (size_t)(q0 + wid * 32 + 16 + l15) * HDIM + kc * 32 + l4 * 8);
  }

  f32x4 oa[8] = {}, ob[8] = {};
  float la = 0.f, lb = 0.f;

  auto stage = [&](int kv0, int bufIdx) {
    u16_t* Kl = lds + bufIdx * 8192;
    u16_t* Vl = lds + 16384 + bufIdx * 8192;
#pragma unroll
    for (int ss = 0; ss < 4; ++ss) {
      int slot = tid + ss * 256;
      int rK = slot >> 4;
      int cK = (slot & 15) ^ ((rK & 3) | (((rK >> 3) & 1) << 2));
      __builtin_amdgcn_global_load_lds(
          (const __attribute__((address_space(1))) u32_t*)(Khead + (size_t)(kv0 + rK) * HDIM + cK * 8),
          (__attribute__((address_space(3))) u32_t*)(Kl + slot * 8), 16, 0, 0);
      int rV = slot >> 3, cV = (slot & 7) ^ (rV & 7);
      __builtin_amdgcn_global_load_lds(
          (const __attribute__((address_space(1))) u32_t*)(Vhead + (size_t)rV * SEQ + kv0 + cV * 8),
          (__attribute__((address_space(3))) u32_t*)(Vl + slot * 8), 16, 0, 0);
    }
  };

  stage(0, 0);

  const int NT = SEQ / 64;
  for (int t = 0; t < NT; ++t) {
    int cur = t & 1;
    if (t + 1 < NT) {
      stage((t + 1) * 64, cur ^ 1);
      asm volatile("s_waitcnt vmcnt(8)" ::: "memory");
    } else {
      asm volatile("s_waitcnt vmcnt(0)" ::: "memory");
    }
    __builtin_amdgcn_s_barrier();
    __builtin_amdgcn_sched_barrier(0);

    const u16_t* Kcur = lds + cur * 8192;
    const u16_t* Vcur = lds + 16384 + cur * 8192;

    f32x4 sa[4] = {}, sb[4] = {};
    __builtin_amdgcn_s_setprio(1);
#pragma unroll
    for (int kc = 0; kc < 4; ++kc) {
#pragma unroll
      for (int kvb = 0; kvb < 4; ++kvb) {
        int row = (l15 >> 2) * 8 + ((kvb & 1) << 2) + (l15 & 3) + ((kvb >> 1) << 5);
        int chunk = ((kc << 2) + l4) ^ (l15 & 7);
        bf16x8 kf = *(const bf16x8*)(Kcur + row * 128 + chunk * 8);
        sa[kvb] = __builtin_amdgcn_mfma_f32_16x16x32_bf16(kf, qfa[kc], sa[kvb], 0, 0, 0);
        sb[kvb] = __builtin_amdgcn_mfma_f32_16x16x32_bf16(kf, qfb[kc], sb[kvb], 0, 0, 0);
      }
    }
    __builtin_amdgcn_s_setprio(0);

    bf16x4 pa[4], pb[4];
#pragma unroll
    for (int kvb = 0; kvb < 4; ++kvb) {
#pragma unroll
      for (int r = 0; r < 4; ++r) {
        float ea = __builtin_amdgcn_exp2f(sa[kvb][r]);
        float eb = __builtin_amdgcn_exp2f(sb[kvb][r]);
        la += ea; lb += eb;
        pa[kvb][r] = (__bf16)ea;
        pb[kvb][r] = (__bf16)eb;
      }
    }

    bf16x8 pfa[2], pfb[2];
#pragma unroll
    for (int kc2 = 0; kc2 < 2; ++kc2) {
      uint2 alo = __builtin_bit_cast(uint2, pa[kc2 * 2]);
      uint2 ahi = __builtin_bit_cast(uint2, pa[kc2 * 2 + 1]);
      uint4 wa; wa.x = alo.x; wa.y = alo.y; wa.z = ahi.x; wa.w = ahi.y;
      pfa[kc2] = __builtin_bit_cast(bf16x8, wa);
      uint2 blo = __builtin_bit_cast(uint2, pb[kc2 * 2]);
      uint2 bhi = __builtin_bit_cast(uint2, pb[kc2 * 2 + 1]);
      uint4 wb; wb.x = blo.x; wb.y = blo.y; wb.z = bhi.x; wb.w = bhi.y;
      pfb[kc2] = __builtin_bit_cast(bf16x8, wb);
    }

    __builtin_amdgcn_s_setprio(1);
#pragma unroll
    for (int kc2 = 0; kc2 < 2; ++kc2) {
#pragma unroll
      for (int dcb = 0; dcb < 8; ++dcb) {
        int chunk = ((kc2 << 2) + l4) ^ (l15 & 7);
        bf16x8 vf = *(const bf16x8*)(Vcur + (dcb * 16 + l15) * 64 + chunk * 8);
        oa[dcb] = __builtin_amdgcn_mfma_f32_16x16x32_bf16(vf, pfa[kc2], oa[dcb], 0, 0, 0);
        ob[dcb] = __builtin_amdgcn_mfma_f32_16x16x32_bf16(vf, pfb[kc2], ob[dcb], 0, 0, 0);
      }
    }
    __builtin_amdgcn_s_setprio(0);

    __builtin_amdgcn_sched_barrier(0);
    __builtin_amdgcn_s_barrier();
  }

  la += __shfl_xor(la, 16); la += __shfl_xor(la, 32);
  lb += __shfl_xor(lb, 16); lb += __shfl_xor(lb, 32);
  float inva = 1.0f / la, invb = 1.0f / lb;

#pragma unroll
  for (int half = 0; half < 2; ++half) {
    u16_t* Owave = lds + half * 8704 + wid * 2176;
    const f32x4* oacc = half ? ob : oa;
    float inv = half ? invb : inva;
#pragma unroll
    for (int dcb = 0; dcb < 8; ++dcb) {
      bf16x4 ov;
#pragma unroll
      for (int r = 0; r < 4; ++r) ov[r] = (__bf16)(oacc[dcb][r] * inv);
      *(uint2*)(Owave + l15 * 136 + dcb * 16 + l4 * 4) = __builtin_bit_cast(uint2, ov);
    }
#pragma unroll
    for (int pass = 0; pass < 4; ++pass) {
      int rowq = pass * 4 + l4;
      int4 v = *(const int4*)(Owave + rowq * 136 + l15 * 8);
      int s = q0 + wid * 32 + half * 16 + rowq;
      *(int4*)(attn_out + ((size_t)(b * SEQ + s)) * DMODEL + h * HDIM + l15 * 8) = v;
    }
  }
}

// ---------------- launcher ----------------

extern "C" void kernel_launch(void* const* d_in, const int* in_sizes, int n_in,
                              void* d_out, int out_size, void* d_ws, size_t ws_size,
                              hipStream_t stream) {
  (void)in_sizes; (void)n_in; (void)out_size; (void)ws_size;
  const float* x  = (const float*)d_in[0];
  const float* rf = (const float*)d_in[1];
  const float* Wq = (const float*)d_in[2];
  const float* bq = (const float*)d_in[3];
  const float* Wk = (const float*)d_in[4];
  const float* bk = (const float*)d_in[5];
  const float* Wv = (const float*)d_in[6];
  const float* bv = (const float*)d_in[7];
  const float* Wo = (const float*)d_in[8];
  const float* bo = (const float*)d_in[9];
  float* out = (float*)d_out;

  char* ws = (char*)d_ws;
  u16_t* xb    = (u16_t*)ws;  ws += (size_t)MROWS * DMODEL * 2;
  u16_t* Wqkvt = (u16_t*)ws;  ws += (size_t)NQKV * DMODEL * 2;
  u16_t* Wot   = (u16_t*)ws;  ws += (size_t)DMODEL * DMODEL * 2;
  float* bqkv  = (float*)ws;  ws += (size_t)NQKV * 4;
  float* cosT  = (float*)ws;  ws += (size_t)SEQ * (HDIM / 2) * 4;
  float* sinT  = (float*)ws;  ws += (size_t)SEQ * (HDIM / 2) * 4;
  u16_t* Qb    = (u16_t*)ws;  ws += (size_t)NB * NHEAD * SEQ * HDIM * 2;
  u16_t* Kb    = (u16_t*)ws;  ws += (size_t)NB * NGRP * SEQ * HDIM * 2;
  u16_t* Vt    = (u16_t*)ws;  ws += (size_t)NB * NGRP * HDIM * SEQ * 2;
  u16_t* attn  = xb;  // alias: xb dead after GEMM1 (strict stream ordering)

  k_cast_x<<<MROWS * DMODEL / 1024, 256, 0, stream>>>(x, xb);
  k_tables<<<SEQ * (HDIM / 2) / 256, 256, 0, stream>>>(rf, cosT, sinT);
  k_bias<<<NQKV / 256, 256, 0, stream>>>(bq, bk, bv, bqkv);

  dim3 tgq(DMODEL / 64, DMODEL / 64);
  dim3 tgk(NKV / 64, DMODEL / 64);
  k_transpose_cast<<<tgq, 256, 0, stream>>>(Wq, DMODEL, Wqkvt, DMODEL);
  k_transpose_cast<<<tgk, 256, 0, stream>>>(Wk, NKV, Wqkvt + (size_t)DMODEL * DMODEL, DMODEL);
  k_transpose_cast<<<tgk, 256, 0, stream>>>(Wv, NKV, Wqkvt + (size_t)(DMODEL + NKV) * DMODEL, DMODEL);
  k_transpose_cast<<<tgq, 256, 0, stream>>>(Wo, DMODEL, Wot, DMODEL);

  // GEMM1: 4096 x 3072 x 2048 -> (32*24)=768 blocks (div by 8)
  k_gemm<1><<<dim3((MROWS / 128) * (NQKV / 128)), 256, 0, stream>>>(
      xb, Wqkvt, bqkv, nullptr, Qb, Kb, Vt, cosT, sinT, MROWS, NQKV, DMODEL);

  dim3 ga(SEQ / 128, NB * NHEAD);
  k_attn<<<ga, 256, 0, stream>>>(Qb, Kb, Vt, attn);

  // GEMM2: 4096 x 2048 x 2048 -> (32*16)=512 blocks
  k_gemm<0><<<dim3((MROWS / 128) * (DMODEL / 128)), 256, 0, stream>>>(
      attn, Wot, bo, out, nullptr, nullptr, nullptr, nullptr, nullptr, MROWS, DMODEL, DMODEL);
}

// Round 10
// 218.040 us; speedup vs baseline: 1.0661x; 1.0340x over previous
//
#include <hip/hip_runtime.h>
#include <cstdint>
#include <cstddef>

#define NB 2
#define SEQ 2048
#define DMODEL 2048
#define NHEAD 16
#define HDIM 128
#define NGRP 4
#define NKV (NGRP * HDIM)          // 512
#define NQKV (DMODEL + 2 * NKV)    // 3072
#define MROWS (NB * SEQ)           // 4096
// 1/sqrt(128) * log2(e): Q pre-scale so softmax uses exp2 directly
#define QSCALE_LOG2E 0.12751743f

typedef unsigned short u16_t;
typedef unsigned int u32_t;
typedef __bf16 bf16x8 __attribute__((ext_vector_type(8)));
typedef __bf16 bf16x4 __attribute__((ext_vector_type(4)));
typedef float f32x4 __attribute__((ext_vector_type(4)));

static __device__ __forceinline__ u16_t f2bf(float f) {
  u32_t u = __builtin_bit_cast(u32_t, f);
  u32_t r = u + 0x7FFFu + ((u >> 16) & 1u);
  return (u16_t)(r >> 16);
}

// ---------------- prep kernels ----------------

__global__ void k_cast_x(const float* __restrict__ x, u16_t* __restrict__ xb) {
  int i = blockIdx.x * 256 + threadIdx.x;          // group of 4 floats
  float4 v = ((const float4*)x)[i];
  uint2 pk;
  pk.x = (u32_t)f2bf(v.x) | ((u32_t)f2bf(v.y) << 16);
  pk.y = (u32_t)f2bf(v.z) | ((u32_t)f2bf(v.w) << 16);
  ((uint2*)xb)[i] = pk;
}

__global__ void k_tables(const float* __restrict__ rf, float* __restrict__ cosT,
                         float* __restrict__ sinT) {
  int i = blockIdx.x * 256 + threadIdx.x;          // < SEQ*HDIM/2
  float f = rf[i];
  cosT[i] = cosf(f);
  sinT[i] = sinf(f);
}

__global__ void k_bias(const float* __restrict__ bq, const float* __restrict__ bk,
                       const float* __restrict__ bv, float* __restrict__ bqkv) {
  int i = blockIdx.x * 256 + threadIdx.x;          // < NQKV
  float v = (i < DMODEL) ? bq[i] : (i < DMODEL + NKV ? bk[i - DMODEL] : bv[i - DMODEL - NKV]);
  bqkv[i] = v;
}

// W: [K][N] fp32 row-major -> Wt: [N][K] bf16 row-major
__global__ void k_transpose_cast(const float* __restrict__ W, int N,
                                 u16_t* __restrict__ Wt, int K) {
  __shared__ float tile[64][65];
  int n0 = blockIdx.x * 64, k0 = blockIdx.y * 64;
  int t = threadIdx.x;
#pragma unroll
  for (int pass = 0; pass < 4; ++pass) {
    int slot = pass * 256 + t;
    int r = slot >> 4, c4 = (slot & 15) * 4;
    float4 v = *(const float4*)(W + (size_t)(k0 + r) * N + n0 + c4);
    tile[r][c4] = v.x; tile[r][c4 + 1] = v.y; tile[r][c4 + 2] = v.z; tile[r][c4 + 3] = v.w;
  }
  __syncthreads();
  int nr = t >> 2, seg = t & 3;
  alignas(16) u16_t o[16];
#pragma unroll
  for (int kk = 0; kk < 16; ++kk) o[kk] = f2bf(tile[seg * 16 + kk][nr]);
  u16_t* dst = Wt + (size_t)(n0 + nr) * K + k0 + seg * 16;
  ((int4*)dst)[0] = ((const int4*)o)[0];
  ((int4*)dst)[1] = ((const int4*)o)[1];
}

// ---------------- GEMM: C[M][N] = A[M][K](bf16) * Bt[N][K](bf16)^T + bias ----------
// 128x128 tile, BK=32, 256 threads (4 waves, 2x2), per-wave 64x64 (acc[4][4]).
// Round-10:
//  - plain 2D grid (R6 mapping; default round-robin XCD gave best L2/L3 locality:
//    FETCH 77MB vs 144MB with explicit stripes -- R9 regression reverted)
//  - R9's proven two-barrier counted ledger:
//      prologue stage(0), stage(1);
//      per tile t: vmcnt(4) -> s_barrier #1 -> compute(slot t&1)
//                  -> s_barrier #2 -> stage(t+2)
//  - tight LDS slots (32KB total, was 64KB with a stride bug) -> more blocks/CU
//  - T2 XOR-swizzle (16B chunk c' = c^(row&3), pre-swizzled on the GLOBAL source;
//    reads use chunk = l4^(l15&3)): fragment reads go 8-way -> 2-way conflicts.
// EPI 0: fp32 out.  EPI 1: QKV epilogue (RoPE, Q pre-scaled, V transposed).

template <int EPI>
__global__ __launch_bounds__(256, 2) void k_gemm(
    const u16_t* __restrict__ A, const u16_t* __restrict__ Bt, const float* __restrict__ bias,
    float* __restrict__ Cout, u16_t* __restrict__ Qb, u16_t* __restrict__ Kb,
    u16_t* __restrict__ Vt, const float* __restrict__ cosT, const float* __restrict__ sinT,
    int M, int N, int K) {
  // u16 units: A slot0 [0,4096), A slot1 [4096,8192), B slot0 [8192,12288), B slot1 [12288,16384)
  __shared__ u16_t lds[16384];
  int tid = threadIdx.x;
  int wid = tid >> 6, lane = tid & 63;
  int l15 = lane & 15, l4 = lane >> 4;
  int wrow = wid >> 1, wcol = wid & 1;

  int m0 = blockIdx.y << 7, n0 = blockIdx.x << 7;

  f32x4 acc[4][4] = {};

  // stage K-tile t into slot (t&1): A[128][32], B[128][32]; 16B chunks, source
  // pre-swizzled c' = c ^ (row&3), LDS dest linear. 4 VMEM instr per wave.
  auto stage = [&](int t) {
    u16_t* Al = lds + (t & 1) * 4096;
    u16_t* Bl = lds + 8192 + (t & 1) * 4096;
    int kbase = t * 32;
#pragma unroll
    for (int ss = 0; ss < 2; ++ss) {
      int slot = tid + ss * 256;
      int row = slot >> 2, c = slot & 3;
      int cs = c ^ (row & 3);
      __builtin_amdgcn_global_load_lds(
          (const __attribute__((address_space(1))) u32_t*)(A + (size_t)(m0 + row) * K + kbase + cs * 8),
          (__attribute__((address_space(3))) u32_t*)(Al + slot * 8), 16, 0, 0);
      __builtin_amdgcn_global_load_lds(
          (const __attribute__((address_space(1))) u32_t*)(Bt + (size_t)(n0 + row) * K + kbase + cs * 8),
          (__attribute__((address_space(3))) u32_t*)(Bl + slot * 8), 16, 0, 0);
    }
  };

  stage(0);
  stage(1);

  const int NT = K >> 5;   // 64
  for (int t = 0; t < NT; ++t) {
    if (t == NT - 1) {
      asm volatile("s_waitcnt vmcnt(0)" ::: "memory");
    } else {
      asm volatile("s_waitcnt vmcnt(4)" ::: "memory");   // tile t landed; t+1 in flight
    }
    __builtin_amdgcn_s_barrier();                        // #1: slot (t&1) valid
    __builtin_amdgcn_sched_barrier(0);

    const u16_t* Acur = lds + (t & 1) * 4096;
    const u16_t* Bcur = lds + 8192 + (t & 1) * 4096;

    int chunk = l4 ^ (l15 & 3);                          // swizzled k-chunk
    bf16x8 af[4], bfr[4];
#pragma unroll
    for (int i = 0; i < 4; ++i)
      af[i] = *(const bf16x8*)(Acur + (wrow * 64 + i * 16 + l15) * 32 + chunk * 8);
#pragma unroll
    for (int j = 0; j < 4; ++j)
      bfr[j] = *(const bf16x8*)(Bcur + (wcol * 64 + j * 16 + l15) * 32 + chunk * 8);

    __builtin_amdgcn_s_setprio(1);
#pragma unroll
    for (int i = 0; i < 4; ++i)
#pragma unroll
      for (int j = 0; j < 4; ++j)
        acc[i][j] = __builtin_amdgcn_mfma_f32_16x16x32_bf16(af[i], bfr[j], acc[i][j], 0, 0, 0);
    __builtin_amdgcn_s_setprio(0);

    __builtin_amdgcn_sched_barrier(0);
    __builtin_amdgcn_s_barrier();                        // #2: slot (t&1) free
    __builtin_amdgcn_sched_barrier(0);
    if (t + 2 < NT) stage(t + 2);                        // into slot (t&1)
  }

  if (EPI == 0) {
#pragma unroll
    for (int j = 0; j < 4; ++j) {
      int n = n0 + wcol * 64 + j * 16 + l15;
      float bs = bias[n];
#pragma unroll
      for (int i = 0; i < 4; ++i) {
        int mbase = m0 + wrow * 64 + i * 16 + l4 * 4;
#pragma unroll
        for (int r = 0; r < 4; ++r)
          Cout[(size_t)(mbase + r) * N + n] = acc[i][j][r] + bs;
      }
    }
  } else {
    bool isV = (n0 >= DMODEL + NKV);
    bool isK = (n0 >= DMODEL) && !isV;
#pragma unroll
    for (int j = 0; j < 4; ++j) {
      int n = n0 + wcol * 64 + j * 16 + l15;
      float bs = bias[n];
      int d = n & (HDIM - 1);
      int p = d >> 1;
      bool evn = !(d & 1);
#pragma unroll
      for (int i = 0; i < 4; ++i) {
        int mbase = m0 + wrow * 64 + i * 16 + l4 * 4;
        if (isV) {
          int g = (n - DMODEL - NKV) >> 7;
          int b = mbase >> 11, s0 = mbase & (SEQ - 1);
          u16_t o[4];
#pragma unroll
          for (int r = 0; r < 4; ++r) o[r] = f2bf(acc[i][j][r] + bs);
          uint2 pk;
          pk.x = (u32_t)o[0] | ((u32_t)o[1] << 16);
          pk.y = (u32_t)o[2] | ((u32_t)o[3] << 16);
          *(uint2*)(Vt + ((size_t)(b * NGRP + g) * HDIM + d) * SEQ + s0) = pk;
        } else {
#pragma unroll
          for (int r = 0; r < 4; ++r) {
            int m = mbase + r;
            int b = m >> 11, s = m & (SEQ - 1);
            float val = acc[i][j][r] + bs;
            float pv = __shfl_xor(val, 1);
            float c = cosT[s * (HDIM / 2) + p];
            float sn = sinT[s * (HDIM / 2) + p];
            float outv = evn ? (val * c - pv * sn) : (pv * sn + val * c);
            if (isK) {
              int g = (n - DMODEL) >> 7;
              Kb[((size_t)(b * NGRP + g) * SEQ + s) * HDIM + d] = f2bf(outv);
            } else {
              int h = n >> 7;
              Qb[((size_t)(b * NHEAD + h) * SEQ + s) * HDIM + d] = f2bf(outv * QSCALE_LOG2E);
            }
          }
        }
      }
    }
  }
}

// ---------------- flash attention (unchanged from round 6) ----------------

__global__ __launch_bounds__(256) void k_attn(
    const u16_t* __restrict__ Qb, const u16_t* __restrict__ Kb, const u16_t* __restrict__ Vt,
    u16_t* __restrict__ attn_out) {
  __shared__ u16_t lds[32768];

  int tid = threadIdx.x, wid = tid >> 6, lane = tid & 63;
  int l15 = lane & 15, l4 = lane >> 4;
  int bh = blockIdx.y;
  int b = bh >> 4, h = bh & 15, g = h >> 2;
  int q0 = blockIdx.x * 128;
  const u16_t* Qhead = Qb + (size_t)(b * NHEAD + h) * SEQ * HDIM;
  const u16_t* Khead = Kb + (size_t)(b * NGRP + g) * SEQ * HDIM;
  const u16_t* Vhead = Vt + (size_t)(b * NGRP + g) * HDIM * SEQ;

  bf16x8 qfa[4], qfb[4];
#pragma unroll
  for (int kc = 0; kc < 4; ++kc) {
    qfa[kc] = *(const bf16x8*)(Qhead + (size_t)(q0 + wid * 32 + l15) * HDIM + kc * 32 + l4 * 8);
    qfb[kc] = *(const bf16x8*)(Qhead + (size_t)(q0 + wid * 32 + 16 + l15) * HDIM + kc * 32 + l4 * 8);
  }

  f32x4 oa[8] = {}, ob[8] = {};
  float la = 0.f, lb = 0.f;

  auto stage = [&](int kv0, int bufIdx) {
    u16_t* Kl = lds + bufIdx * 8192;
    u16_t* Vl = lds + 16384 + bufIdx * 8192;
#pragma unroll
    for (int ss = 0; ss < 4; ++ss) {
      int slot = tid + ss * 256;
      int rK = slot >> 4;
      int cK = (slot & 15) ^ ((rK & 3) | (((rK >> 3) & 1) << 2));
      __builtin_amdgcn_global_load_lds(
          (const __attribute__((address_space(1))) u32_t*)(Khead + (size_t)(kv0 + rK) * HDIM + cK * 8),
          (__attribute__((address_space(3))) u32_t*)(Kl + slot * 8), 16, 0, 0);
      int rV = slot >> 3, cV = (slot & 7) ^ (rV & 7);
      __builtin_amdgcn_global_load_lds(
          (const __attribute__((address_space(1))) u32_t*)(Vhead + (size_t)rV * SEQ + kv0 + cV * 8),
          (__attribute__((address_space(3))) u32_t*)(Vl + slot * 8), 16, 0, 0);
    }
  };

  stage(0, 0);

  const int NT = SEQ / 64;
  for (int t = 0; t < NT; ++t) {
    int cur = t & 1;
    if (t + 1 < NT) {
      stage((t + 1) * 64, cur ^ 1);
      asm volatile("s_waitcnt vmcnt(8)" ::: "memory");
    } else {
      asm volatile("s_waitcnt vmcnt(0)" ::: "memory");
    }
    __builtin_amdgcn_s_barrier();
    __builtin_amdgcn_sched_barrier(0);

    const u16_t* Kcur = lds + cur * 8192;
    const u16_t* Vcur = lds + 16384 + cur * 8192;

    f32x4 sa[4] = {}, sb[4] = {};
    __builtin_amdgcn_s_setprio(1);
#pragma unroll
    for (int kc = 0; kc < 4; ++kc) {
#pragma unroll
      for (int kvb = 0; kvb < 4; ++kvb) {
        int row = (l15 >> 2) * 8 + ((kvb & 1) << 2) + (l15 & 3) + ((kvb >> 1) << 5);
        int chunk = ((kc << 2) + l4) ^ (l15 & 7);
        bf16x8 kf = *(const bf16x8*)(Kcur + row * 128 + chunk * 8);
        sa[kvb] = __builtin_amdgcn_mfma_f32_16x16x32_bf16(kf, qfa[kc], sa[kvb], 0, 0, 0);
        sb[kvb] = __builtin_amdgcn_mfma_f32_16x16x32_bf16(kf, qfb[kc], sb[kvb], 0, 0, 0);
      }
    }
    __builtin_amdgcn_s_setprio(0);

    bf16x4 pa[4], pb[4];
#pragma unroll
    for (int kvb = 0; kvb < 4; ++kvb) {
#pragma unroll
      for (int r = 0; r < 4; ++r) {
        float ea = __builtin_amdgcn_exp2f(sa[kvb][r]);
        float eb = __builtin_amdgcn_exp2f(sb[kvb][r]);
        la += ea; lb += eb;
        pa[kvb][r] = (__bf16)ea;
        pb[kvb][r] = (__bf16)eb;
      }
    }

    bf16x8 pfa[2], pfb[2];
#pragma unroll
    for (int kc2 = 0; kc2 < 2; ++kc2) {
      uint2 alo = __builtin_bit_cast(uint2, pa[kc2 * 2]);
      uint2 ahi = __builtin_bit_cast(uint2, pa[kc2 * 2 + 1]);
      uint4 wa; wa.x = alo.x; wa.y = alo.y; wa.z = ahi.x; wa.w = ahi.y;
      pfa[kc2] = __builtin_bit_cast(bf16x8, wa);
      uint2 blo = __builtin_bit_cast(uint2, pb[kc2 * 2]);
      uint2 bhi = __builtin_bit_cast(uint2, pb[kc2 * 2 + 1]);
      uint4 wb; wb.x = blo.x; wb.y = blo.y; wb.z = bhi.x; wb.w = bhi.y;
      pfb[kc2] = __builtin_bit_cast(bf16x8, wb);
    }

    __builtin_amdgcn_s_setprio(1);
#pragma unroll
    for (int kc2 = 0; kc2 < 2; ++kc2) {
#pragma unroll
      for (int dcb = 0; dcb < 8; ++dcb) {
        int chunk = ((kc2 << 2) + l4) ^ (l15 & 7);
        bf16x8 vf = *(const bf16x8*)(Vcur + (dcb * 16 + l15) * 64 + chunk * 8);
        oa[dcb] = __builtin_amdgcn_mfma_f32_16x16x32_bf16(vf, pfa[kc2], oa[dcb], 0, 0, 0);
        ob[dcb] = __builtin_amdgcn_mfma_f32_16x16x32_bf16(vf, pfb[kc2], ob[dcb], 0, 0, 0);
      }
    }
    __builtin_amdgcn_s_setprio(0);

    __builtin_amdgcn_sched_barrier(0);
    __builtin_amdgcn_s_barrier();
  }

  la += __shfl_xor(la, 16); la += __shfl_xor(la, 32);
  lb += __shfl_xor(lb, 16); lb += __shfl_xor(lb, 32);
  float inva = 1.0f / la, invb = 1.0f / lb;

#pragma unroll
  for (int half = 0; half < 2; ++half) {
    u16_t* Owave = lds + half * 8704 + wid * 2176;
    const f32x4* oacc = half ? ob : oa;
    float inv = half ? invb : inva;
#pragma unroll
    for (int dcb = 0; dcb < 8; ++dcb) {
      bf16x4 ov;
#pragma unroll
      for (int r = 0; r < 4; ++r) ov[r] = (__bf16)(oacc[dcb][r] * inv);
      *(uint2*)(Owave + l15 * 136 + dcb * 16 + l4 * 4) = __builtin_bit_cast(uint2, ov);
    }
#pragma unroll
    for (int pass = 0; pass < 4; ++pass) {
      int rowq = pass * 4 + l4;
      int4 v = *(const int4*)(Owave + rowq * 136 + l15 * 8);
      int s = q0 + wid * 32 + half * 16 + rowq;
      *(int4*)(attn_out + ((size_t)(b * SEQ + s)) * DMODEL + h * HDIM + l15 * 8) = v;
    }
  }
}

// ---------------- launcher ----------------

extern "C" void kernel_launch(void* const* d_in, const int* in_sizes, int n_in,
                              void* d_out, int out_size, void* d_ws, size_t ws_size,
                              hipStream_t stream) {
  (void)in_sizes; (void)n_in; (void)out_size; (void)ws_size;
  const float* x  = (const float*)d_in[0];
  const float* rf = (const float*)d_in[1];
  const float* Wq = (const float*)d_in[2];
  const float* bq = (const float*)d_in[3];
  const float* Wk = (const float*)d_in[4];
  const float* bk = (const float*)d_in[5];
  const float* Wv = (const float*)d_in[6];
  const float* bv = (const float*)d_in[7];
  const float* Wo = (const float*)d_in[8];
  const float* bo = (const float*)d_in[9];
  float* out = (float*)d_out;

  char* ws = (char*)d_ws;
  u16_t* xb    = (u16_t*)ws;  ws += (size_t)MROWS * DMODEL * 2;
  u16_t* Wqkvt = (u16_t*)ws;  ws += (size_t)NQKV * DMODEL * 2;
  u16_t* Wot   = (u16_t*)ws;  ws += (size_t)DMODEL * DMODEL * 2;
  float* bqkv  = (float*)ws;  ws += (size_t)NQKV * 4;
  float* cosT  = (float*)ws;  ws += (size_t)SEQ * (HDIM / 2) * 4;
  float* sinT  = (float*)ws;  ws += (size_t)SEQ * (HDIM / 2) * 4;
  u16_t* Qb    = (u16_t*)ws;  ws += (size_t)NB * NHEAD * SEQ * HDIM * 2;
  u16_t* Kb    = (u16_t*)ws;  ws += (size_t)NB * NGRP * SEQ * HDIM * 2;
  u16_t* Vt    = (u16_t*)ws;  ws += (size_t)NB * NGRP * HDIM * SEQ * 2;
  u16_t* attn  = xb;  // alias: xb dead after GEMM1 (strict stream ordering)

  k_cast_x<<<MROWS * DMODEL / 1024, 256, 0, stream>>>(x, xb);
  k_tables<<<SEQ * (HDIM / 2) / 256, 256, 0, stream>>>(rf, cosT, sinT);
  k_bias<<<NQKV / 256, 256, 0, stream>>>(bq, bk, bv, bqkv);

  dim3 tgq(DMODEL / 64, DMODEL / 64);
  dim3 tgk(NKV / 64, DMODEL / 64);
  k_transpose_cast<<<tgq, 256, 0, stream>>>(Wq, DMODEL, Wqkvt, DMODEL);
  k_transpose_cast<<<tgk, 256, 0, stream>>>(Wk, NKV, Wqkvt + (size_t)DMODEL * DMODEL, DMODEL);
  k_transpose_cast<<<tgk, 256, 0, stream>>>(Wv, NKV, Wqkvt + (size_t)(DMODEL + NKV) * DMODEL, DMODEL);
  k_transpose_cast<<<tgq, 256, 0, stream>>>(Wo, DMODEL, Wot, DMODEL);

  // GEMM1: 4096 x 3072 x 2048
  k_gemm<1><<<dim3(NQKV / 128, MROWS / 128), 256, 0, stream>>>(
      xb, Wqkvt, bqkv, nullptr, Qb, Kb, Vt, cosT, sinT, MROWS, NQKV, DMODEL);

  dim3 ga(SEQ / 128, NB * NHEAD);
  k_attn<<<ga, 256, 0, stream>>>(Qb, Kb, Vt, attn);

  // GEMM2: 4096 x 2048 x 2048
  k_gemm<0><<<dim3(DMODEL / 128, MROWS / 128), 256, 0, stream>>>(
      attn, Wot, bo, out, nullptr, nullptr, nullptr, nullptr, nullptr, MROWS, DMODEL, DMODEL);
}

// Round 11
// 206.257 us; speedup vs baseline: 1.1270x; 1.0571x over previous
//
#include <hip/hip_runtime.h>
#include <cstdint>
#include <cstddef>

#define NB 2
#define SEQ 2048
#define DMODEL 2048
#define NHEAD 16
#define HDIM 128
#define NGRP 4
#define NKV (NGRP * HDIM)          // 512
#define NQKV (DMODEL + 2 * NKV)    // 3072
#define MROWS (NB * SEQ)           // 4096
// 1/sqrt(128) * log2(e): Q pre-scale so softmax uses exp2 directly
#define QSCALE_LOG2E 0.12751743f

typedef unsigned short u16_t;
typedef unsigned int u32_t;
typedef __bf16 bf16x8 __attribute__((ext_vector_type(8)));
typedef __bf16 bf16x4 __attribute__((ext_vector_type(4)));
typedef float f32x4 __attribute__((ext_vector_type(4)));

static __device__ __forceinline__ u16_t f2bf(float f) {
  u32_t u = __builtin_bit_cast(u32_t, f);
  u32_t r = u + 0x7FFFu + ((u >> 16) & 1u);
  return (u16_t)(r >> 16);
}

// ---------------- prep kernels ----------------

__global__ void k_cast_x(const float* __restrict__ x, u16_t* __restrict__ xb) {
  int i = blockIdx.x * 256 + threadIdx.x;          // group of 4 floats
  float4 v = ((const float4*)x)[i];
  uint2 pk;
  pk.x = (u32_t)f2bf(v.x) | ((u32_t)f2bf(v.y) << 16);
  pk.y = (u32_t)f2bf(v.z) | ((u32_t)f2bf(v.w) << 16);
  ((uint2*)xb)[i] = pk;
}

__global__ void k_tables(const float* __restrict__ rf, float* __restrict__ cosT,
                         float* __restrict__ sinT) {
  int i = blockIdx.x * 256 + threadIdx.x;          // < SEQ*HDIM/2
  float f = rf[i];
  cosT[i] = cosf(f);
  sinT[i] = sinf(f);
}

__global__ void k_bias(const float* __restrict__ bq, const float* __restrict__ bk,
                       const float* __restrict__ bv, float* __restrict__ bqkv) {
  int i = blockIdx.x * 256 + threadIdx.x;          // < NQKV
  float v = (i < DMODEL) ? bq[i] : (i < DMODEL + NKV ? bk[i - DMODEL] : bv[i - DMODEL - NKV]);
  bqkv[i] = v;
}

// W: [K][N] fp32 row-major -> Wt: [N][K] bf16 row-major
__global__ void k_transpose_cast(const float* __restrict__ W, int N,
                                 u16_t* __restrict__ Wt, int K) {
  __shared__ float tile[64][65];
  int n0 = blockIdx.x * 64, k0 = blockIdx.y * 64;
  int t = threadIdx.x;
#pragma unroll
  for (int pass = 0; pass < 4; ++pass) {
    int slot = pass * 256 + t;
    int r = slot >> 4, c4 = (slot & 15) * 4;
    float4 v = *(const float4*)(W + (size_t)(k0 + r) * N + n0 + c4);
    tile[r][c4] = v.x; tile[r][c4 + 1] = v.y; tile[r][c4 + 2] = v.z; tile[r][c4 + 3] = v.w;
  }
  __syncthreads();
  int nr = t >> 2, seg = t & 3;
  alignas(16) u16_t o[16];
#pragma unroll
  for (int kk = 0; kk < 16; ++kk) o[kk] = f2bf(tile[seg * 16 + kk][nr]);
  u16_t* dst = Wt + (size_t)(n0 + nr) * K + k0 + seg * 16;
  ((int4*)dst)[0] = ((const int4*)o)[0];
  ((int4*)dst)[1] = ((const int4*)o)[1];
}

// ---------------- GEMM (unchanged from round 10) ----------------
// 128x128 tile, BK=32, 256 threads (4 waves, 2x2), per-wave 64x64 (acc[4][4]).
// Plain 2D grid; two-barrier counted ledger; tight 32KB LDS; T2 XOR swizzle.

template <int EPI>
__global__ __launch_bounds__(256, 2) void k_gemm(
    const u16_t* __restrict__ A, const u16_t* __restrict__ Bt, const float* __restrict__ bias,
    float* __restrict__ Cout, u16_t* __restrict__ Qb, u16_t* __restrict__ Kb,
    u16_t* __restrict__ Vt, const float* __restrict__ cosT, const float* __restrict__ sinT,
    int M, int N, int K) {
  __shared__ u16_t lds[16384];
  int tid = threadIdx.x;
  int wid = tid >> 6, lane = tid & 63;
  int l15 = lane & 15, l4 = lane >> 4;
  int wrow = wid >> 1, wcol = wid & 1;

  int m0 = blockIdx.y << 7, n0 = blockIdx.x << 7;

  f32x4 acc[4][4] = {};

  auto stage = [&](int t) {
    u16_t* Al = lds + (t & 1) * 4096;
    u16_t* Bl = lds + 8192 + (t & 1) * 4096;
    int kbase = t * 32;
#pragma unroll
    for (int ss = 0; ss < 2; ++ss) {
      int slot = tid + ss * 256;
      int row = slot >> 2, c = slot & 3;
      int cs = c ^ (row & 3);
      __builtin_amdgcn_global_load_lds(
          (const __attribute__((address_space(1))) u32_t*)(A + (size_t)(m0 + row) * K + kbase + cs * 8),
          (__attribute__((address_space(3))) u32_t*)(Al + slot * 8), 16, 0, 0);
      __builtin_amdgcn_global_load_lds(
          (const __attribute__((address_space(1))) u32_t*)(Bt + (size_t)(n0 + row) * K + kbase + cs * 8),
          (__attribute__((address_space(3))) u32_t*)(Bl + slot * 8), 16, 0, 0);
    }
  };

  stage(0);
  stage(1);

  const int NT = K >> 5;   // 64
  for (int t = 0; t < NT; ++t) {
    if (t == NT - 1) {
      asm volatile("s_waitcnt vmcnt(0)" ::: "memory");
    } else {
      asm volatile("s_waitcnt vmcnt(4)" ::: "memory");
    }
    __builtin_amdgcn_s_barrier();
    __builtin_amdgcn_sched_barrier(0);

    const u16_t* Acur = lds + (t & 1) * 4096;
    const u16_t* Bcur = lds + 8192 + (t & 1) * 4096;

    int chunk = l4 ^ (l15 & 3);
    bf16x8 af[4], bfr[4];
#pragma unroll
    for (int i = 0; i < 4; ++i)
      af[i] = *(const bf16x8*)(Acur + (wrow * 64 + i * 16 + l15) * 32 + chunk * 8);
#pragma unroll
    for (int j = 0; j < 4; ++j)
      bfr[j] = *(const bf16x8*)(Bcur + (wcol * 64 + j * 16 + l15) * 32 + chunk * 8);

    __builtin_amdgcn_s_setprio(1);
#pragma unroll
    for (int i = 0; i < 4; ++i)
#pragma unroll
      for (int j = 0; j < 4; ++j)
        acc[i][j] = __builtin_amdgcn_mfma_f32_16x16x32_bf16(af[i], bfr[j], acc[i][j], 0, 0, 0);
    __builtin_amdgcn_s_setprio(0);

    __builtin_amdgcn_sched_barrier(0);
    __builtin_amdgcn_s_barrier();
    __builtin_amdgcn_sched_barrier(0);
    if (t + 2 < NT) stage(t + 2);
  }

  if (EPI == 0) {
#pragma unroll
    for (int j = 0; j < 4; ++j) {
      int n = n0 + wcol * 64 + j * 16 + l15;
      float bs = bias[n];
#pragma unroll
      for (int i = 0; i < 4; ++i) {
        int mbase = m0 + wrow * 64 + i * 16 + l4 * 4;
#pragma unroll
        for (int r = 0; r < 4; ++r)
          Cout[(size_t)(mbase + r) * N + n] = acc[i][j][r] + bs;
      }
    }
  } else {
    bool isV = (n0 >= DMODEL + NKV);
    bool isK = (n0 >= DMODEL) && !isV;
#pragma unroll
    for (int j = 0; j < 4; ++j) {
      int n = n0 + wcol * 64 + j * 16 + l15;
      float bs = bias[n];
      int d = n & (HDIM - 1);
      int p = d >> 1;
      bool evn = !(d & 1);
#pragma unroll
      for (int i = 0; i < 4; ++i) {
        int mbase = m0 + wrow * 64 + i * 16 + l4 * 4;
        if (isV) {
          int g = (n - DMODEL - NKV) >> 7;
          int b = mbase >> 11, s0 = mbase & (SEQ - 1);
          u16_t o[4];
#pragma unroll
          for (int r = 0; r < 4; ++r) o[r] = f2bf(acc[i][j][r] + bs);
          uint2 pk;
          pk.x = (u32_t)o[0] | ((u32_t)o[1] << 16);
          pk.y = (u32_t)o[2] | ((u32_t)o[3] << 16);
          *(uint2*)(Vt + ((size_t)(b * NGRP + g) * HDIM + d) * SEQ + s0) = pk;
        } else {
#pragma unroll
          for (int r = 0; r < 4; ++r) {
            int m = mbase + r;
            int b = m >> 11, s = m & (SEQ - 1);
            float val = acc[i][j][r] + bs;
            float pv = __shfl_xor(val, 1);
            float c = cosT[s * (HDIM / 2) + p];
            float sn = sinT[s * (HDIM / 2) + p];
            float outv = evn ? (val * c - pv * sn) : (pv * sn + val * c);
            if (isK) {
              int g = (n - DMODEL) >> 7;
              Kb[((size_t)(b * NGRP + g) * SEQ + s) * HDIM + d] = f2bf(outv);
            } else {
              int h = n >> 7;
              Qb[((size_t)(b * NHEAD + h) * SEQ + s) * HDIM + d] = f2bf(outv * QSCALE_LOG2E);
            }
          }
        }
      }
    }
  }
}

// ---------------- flash attention (round 11: cross-tile pipeline) ----------------
// grid (SEQ/128, NB*NHEAD); 4 waves x 32 q rows; KV tile 64, double-buffered.
// Pipeline: per iteration t:  exp/pack(t) [VALU, overlaps landing prefetch]
//   -> vmcnt(0) -> bar#1 -> { PV(t) || QK(t+1) } merged MFMA region
//   -> bar#2 -> stage(t+2).
// Score registers ping-pong (sA/sB <-> tA/tB) via unroll-by-2 (static indexing).
// Slot lifetimes: K(t) read at iter t-1, V(t) at iter t, both before iter t's
// bar#2 which precedes stage(t+2)'s overwrite -- same ledger family as R7/R9/R10.

__global__ __launch_bounds__(256, 2) void k_attn(
    const u16_t* __restrict__ Qb, const u16_t* __restrict__ Kb, const u16_t* __restrict__ Vt,
    u16_t* __restrict__ attn_out) {
  __shared__ u16_t lds[32768];   // K0,K1,V0,V1: 8192 u16 each

  int tid = threadIdx.x, wid = tid >> 6, lane = tid & 63;
  int l15 = lane & 15, l4 = lane >> 4;
  int bh = blockIdx.y;
  int b = bh >> 4, h = bh & 15, g = h >> 2;
  int q0 = blockIdx.x * 128;
  const u16_t* Qhead = Qb + (size_t)(b * NHEAD + h) * SEQ * HDIM;
  const u16_t* Khead = Kb + (size_t)(b * NGRP + g) * SEQ * HDIM;
  const u16_t* Vhead = Vt + (size_t)(b * NGRP + g) * HDIM * SEQ;

  bf16x8 qfa[4], qfb[4];
#pragma unroll
  for (int kc = 0; kc < 4; ++kc) {
    qfa[kc] = *(const bf16x8*)(Qhead + (size_t)(q0 + wid * 32 + l15) * HDIM + kc * 32 + l4 * 8);
    qfb[kc] = *(const bf16x8*)(Qhead + (size_t)(q0 + wid * 32 + 16 + l15) * HDIM + kc * 32 + l4 * 8);
  }

  f32x4 oa[8] = {}, ob[8] = {};
  float la = 0.f, lb = 0.f;

  auto stage = [&](int kv0, int bufIdx) {
    u16_t* Kl = lds + bufIdx * 8192;
    u16_t* Vl = lds + 16384 + bufIdx * 8192;
#pragma unroll
    for (int ss = 0; ss < 4; ++ss) {
      int slot = tid + ss * 256;
      int rK = slot >> 4;
      int cK = (slot & 15) ^ ((rK & 3) | (((rK >> 3) & 1) << 2));
      __builtin_amdgcn_global_load_lds(
          (const __attribute__((address_space(1))) u32_t*)(Khead + (size_t)(kv0 + rK) * HDIM + cK * 8),
          (__attribute__((address_space(3))) u32_t*)(Kl + slot * 8), 16, 0, 0);
      int rV = slot >> 3, cV = (slot & 7) ^ (rV & 7);
      __builtin_amdgcn_global_load_lds(
          (const __attribute__((address_space(1))) u32_t*)(Vhead + (size_t)rV * SEQ + kv0 + cV * 8),
          (__attribute__((address_space(3))) u32_t*)(Vl + slot * 8), 16, 0, 0);
    }
  };

  // QK for one tile (reads K slot bufIdx) -> accumulate into (Sa,Sb)
  auto qk = [&](int bufIdx, f32x4 (&Sa)[4], f32x4 (&Sb)[4]) {
    const u16_t* Kcur = lds + bufIdx * 8192;
#pragma unroll
    for (int kc = 0; kc < 4; ++kc) {
#pragma unroll
      for (int kvb = 0; kvb < 4; ++kvb) {
        int row = (l15 >> 2) * 8 + ((kvb & 1) << 2) + (l15 & 3) + ((kvb >> 1) << 5);
        int chunk = ((kc << 2) + l4) ^ (l15 & 7);
        bf16x8 kf = *(const bf16x8*)(Kcur + row * 128 + chunk * 8);
        Sa[kvb] = __builtin_amdgcn_mfma_f32_16x16x32_bf16(kf, qfa[kc], Sa[kvb], 0, 0, 0);
        Sb[kvb] = __builtin_amdgcn_mfma_f32_16x16x32_bf16(kf, qfb[kc], Sb[kvb], 0, 0, 0);
      }
    }
  };

  // max-free softmax: P = exp2(S) -> packed PV B-fragments (zero shuffles)
  auto expand = [&](f32x4 (&Sa)[4], f32x4 (&Sb)[4], bf16x8 (&pfa)[2], bf16x8 (&pfb)[2]) {
    bf16x4 pa[4], pb[4];
#pragma unroll
    for (int kvb = 0; kvb < 4; ++kvb) {
#pragma unroll
      for (int r = 0; r < 4; ++r) {
        float ea = __builtin_amdgcn_exp2f(Sa[kvb][r]);
        float eb = __builtin_amdgcn_exp2f(Sb[kvb][r]);
        la += ea; lb += eb;
        pa[kvb][r] = (__bf16)ea;
        pb[kvb][r] = (__bf16)eb;
      }
    }
#pragma unroll
    for (int kc2 = 0; kc2 < 2; ++kc2) {
      uint2 alo = __builtin_bit_cast(uint2, pa[kc2 * 2]);
      uint2 ahi = __builtin_bit_cast(uint2, pa[kc2 * 2 + 1]);
      uint4 wa; wa.x = alo.x; wa.y = alo.y; wa.z = ahi.x; wa.w = ahi.y;
      pfa[kc2] = __builtin_bit_cast(bf16x8, wa);
      uint2 blo = __builtin_bit_cast(uint2, pb[kc2 * 2]);
      uint2 bhi = __builtin_bit_cast(uint2, pb[kc2 * 2 + 1]);
      uint4 wb; wb.x = blo.x; wb.y = blo.y; wb.z = bhi.x; wb.w = bhi.y;
      pfb[kc2] = __builtin_bit_cast(bf16x8, wb);
    }
  };

  // PV for one tile (reads V slot bufIdx)
  auto pv = [&](int bufIdx, bf16x8 (&pfa)[2], bf16x8 (&pfb)[2]) {
    const u16_t* Vcur = lds + 16384 + bufIdx * 8192;
#pragma unroll
    for (int kc2 = 0; kc2 < 2; ++kc2) {
#pragma unroll
      for (int dcb = 0; dcb < 8; ++dcb) {
        int chunk = ((kc2 << 2) + l4) ^ (l15 & 7);
        bf16x8 vf = *(const bf16x8*)(Vcur + (dcb * 16 + l15) * 64 + chunk * 8);
        oa[dcb] = __builtin_amdgcn_mfma_f32_16x16x32_bf16(vf, pfa[kc2], oa[dcb], 0, 0, 0);
        ob[dcb] = __builtin_amdgcn_mfma_f32_16x16x32_bf16(vf, pfb[kc2], ob[dcb], 0, 0, 0);
      }
    }
  };

  // one pipeline step: exp(t from Ia/Ib), PV(t) || QK(t+1 into Oa/Ob), stage(t+2)
  auto step = [&](int t, f32x4 (&Ia)[4], f32x4 (&Ib)[4], f32x4 (&Oa)[4], f32x4 (&Ob)[4]) {
    bf16x8 pfa[2], pfb[2];
    expand(Ia, Ib, pfa, pfb);                        // VALU while stage(t+1) lands
    asm volatile("s_waitcnt vmcnt(0)" ::: "memory"); // own stage(t+1) landed
    __builtin_amdgcn_s_barrier();                    // all staged: K(t+1),V(t+1) valid
    __builtin_amdgcn_sched_barrier(0);
#pragma unroll
    for (int z = 0; z < 4; ++z)
#pragma unroll
      for (int r = 0; r < 4; ++r) { Oa[z][r] = 0.f; Ob[z][r] = 0.f; }
    __builtin_amdgcn_s_setprio(1);
    pv(t & 1, pfa, pfb);
    qk((t + 1) & 1, Oa, Ob);
    __builtin_amdgcn_s_setprio(0);
    __builtin_amdgcn_sched_barrier(0);
    __builtin_amdgcn_s_barrier();                    // slot (t&1) reads done
    __builtin_amdgcn_sched_barrier(0);
    if (t + 2 < SEQ / 64) stage((t + 2) * 64, t & 1);
  };

  f32x4 sA[4] = {}, sB[4] = {}, tA[4], tB[4];

  stage(0, 0);
  stage(64, 1);
  asm volatile("s_waitcnt vmcnt(8)" ::: "memory");   // slot0 landed; slot1 in flight
  __builtin_amdgcn_s_barrier();
  __builtin_amdgcn_sched_barrier(0);
  qk(0, sA, sB);                                     // scores(0)

  for (int p = 0; p < 15; ++p) {
    step(2 * p, sA, sB, tA, tB);
    step(2 * p + 1, tA, tB, sA, sB);
  }
  step(30, sA, sB, tA, tB);
  {
    bf16x8 pfa[2], pfb[2];
    expand(tA, tB, pfa, pfb);                        // tile 31
    pv(1, pfa, pfb);
  }

  la += __shfl_xor(la, 16); la += __shfl_xor(la, 32);
  lb += __shfl_xor(lb, 16); lb += __shfl_xor(lb, 32);
  float inva = 1.0f / la, invb = 1.0f / lb;

#pragma unroll
  for (int half = 0; half < 2; ++half) {
    u16_t* Owave = lds + half * 8704 + wid * 2176;
    const f32x4* oacc = half ? ob : oa;
    float inv = half ? invb : inva;
#pragma unroll
    for (int dcb = 0; dcb < 8; ++dcb) {
      bf16x4 ov;
#pragma unroll
      for (int r = 0; r < 4; ++r) ov[r] = (__bf16)(oacc[dcb][r] * inv);
      *(uint2*)(Owave + l15 * 136 + dcb * 16 + l4 * 4) = __builtin_bit_cast(uint2, ov);
    }
#pragma unroll
    for (int pass = 0; pass < 4; ++pass) {
      int rowq = pass * 4 + l4;
      int4 v = *(const int4*)(Owave + rowq * 136 + l15 * 8);
      int s = q0 + wid * 32 + half * 16 + rowq;
      *(int4*)(attn_out + ((size_t)(b * SEQ + s)) * DMODEL + h * HDIM + l15 * 8) = v;
    }
  }
}

// ---------------- launcher ----------------

extern "C" void kernel_launch(void* const* d_in, const int* in_sizes, int n_in,
                              void* d_out, int out_size, void* d_ws, size_t ws_size,
                              hipStream_t stream) {
  (void)in_sizes; (void)n_in; (void)out_size; (void)ws_size;
  const float* x  = (const float*)d_in[0];
  const float* rf = (const float*)d_in[1];
  const float* Wq = (const float*)d_in[2];
  const float* bq = (const float*)d_in[3];
  const float* Wk = (const float*)d_in[4];
  const float* bk = (const float*)d_in[5];
  const float* Wv = (const float*)d_in[6];
  const float* bv = (const float*)d_in[7];
  const float* Wo = (const float*)d_in[8];
  const float* bo = (const float*)d_in[9];
  float* out = (float*)d_out;

  char* ws = (char*)d_ws;
  u16_t* xb    = (u16_t*)ws;  ws += (size_t)MROWS * DMODEL * 2;
  u16_t* Wqkvt = (u16_t*)ws;  ws += (size_t)NQKV * DMODEL * 2;
  u16_t* Wot   = (u16_t*)ws;  ws += (size_t)DMODEL * DMODEL * 2;
  float* bqkv  = (float*)ws;  ws += (size_t)NQKV * 4;
  float* cosT  = (float*)ws;  ws += (size_t)SEQ * (HDIM / 2) * 4;
  float* sinT  = (float*)ws;  ws += (size_t)SEQ * (HDIM / 2) * 4;
  u16_t* Qb    = (u16_t*)ws;  ws += (size_t)NB * NHEAD * SEQ * HDIM * 2;
  u16_t* Kb    = (u16_t*)ws;  ws += (size_t)NB * NGRP * SEQ * HDIM * 2;
  u16_t* Vt    = (u16_t*)ws;  ws += (size_t)NB * NGRP * HDIM * SEQ * 2;
  u16_t* attn  = xb;  // alias: xb dead after GEMM1 (strict stream ordering)

  k_cast_x<<<MROWS * DMODEL / 1024, 256, 0, stream>>>(x, xb);
  k_tables<<<SEQ * (HDIM / 2) / 256, 256, 0, stream>>>(rf, cosT, sinT);
  k_bias<<<NQKV / 256, 256, 0, stream>>>(bq, bk, bv, bqkv);

  dim3 tgq(DMODEL / 64, DMODEL / 64);
  dim3 tgk(NKV / 64, DMODEL / 64);
  k_transpose_cast<<<tgq, 256, 0, stream>>>(Wq, DMODEL, Wqkvt, DMODEL);
  k_transpose_cast<<<tgk, 256, 0, stream>>>(Wk, NKV, Wqkvt + (size_t)DMODEL * DMODEL, DMODEL);
  k_transpose_cast<<<tgk, 256, 0, stream>>>(Wv, NKV, Wqkvt + (size_t)(DMODEL + NKV) * DMODEL, DMODEL);
  k_transpose_cast<<<tgq, 256, 0, stream>>>(Wo, DMODEL, Wot, DMODEL);

  // GEMM1: 4096 x 3072 x 2048
  k_gemm<1><<<dim3(NQKV / 128, MROWS / 128), 256, 0, stream>>>(
      xb, Wqkvt, bqkv, nullptr, Qb, Kb, Vt, cosT, sinT, MROWS, NQKV, DMODEL);

  dim3 ga(SEQ / 128, NB * NHEAD);
  k_attn<<<ga, 256, 0, stream>>>(Qb, Kb, Vt, attn);

  // GEMM2: 4096 x 2048 x 2048
  k_gemm<0><<<dim3(DMODEL / 128, MROWS / 128), 256, 0, stream>>>(
      attn, Wot, bo, out, nullptr, nullptr, nullptr, nullptr, nullptr, MROWS, DMODEL, DMODEL);
}

// Round 12
// 199.248 us; speedup vs baseline: 1.1666x; 1.0352x over previous
//
#include <hip/hip_runtime.h>
#include <cstdint>
#include <cstddef>

#define NB 2
#define SEQ 2048
#define DMODEL 2048
#define NHEAD 16
#define HDIM 128
#define NGRP 4
#define NKV (NGRP * HDIM)          // 512
#define NQKV (DMODEL + 2 * NKV)    // 3072
#define MROWS (NB * SEQ)           // 4096
// 1/sqrt(128) * log2(e): Q pre-scale so softmax uses exp2 directly
#define QSCALE_LOG2E 0.12751743f

typedef unsigned short u16_t;
typedef unsigned int u32_t;
typedef __bf16 bf16x8 __attribute__((ext_vector_type(8)));
typedef __bf16 bf16x4 __attribute__((ext_vector_type(4)));
typedef float f32x4 __attribute__((ext_vector_type(4)));

static __device__ __forceinline__ u16_t f2bf(float f) {
  u32_t u = __builtin_bit_cast(u32_t, f);
  u32_t r = u + 0x7FFFu + ((u >> 16) & 1u);
  return (u16_t)(r >> 16);
}

// ---------------- prep kernels ----------------

__global__ void k_cast_x(const float* __restrict__ x, u16_t* __restrict__ xb) {
  int i = blockIdx.x * 256 + threadIdx.x;          // group of 4 floats
  float4 v = ((const float4*)x)[i];
  uint2 pk;
  pk.x = (u32_t)f2bf(v.x) | ((u32_t)f2bf(v.y) << 16);
  pk.y = (u32_t)f2bf(v.z) | ((u32_t)f2bf(v.w) << 16);
  ((uint2*)xb)[i] = pk;
}

__global__ void k_tables(const float* __restrict__ rf, float* __restrict__ cosT,
                         float* __restrict__ sinT) {
  int i = blockIdx.x * 256 + threadIdx.x;          // < SEQ*HDIM/2
  float f = rf[i];
  cosT[i] = cosf(f);
  sinT[i] = sinf(f);
}

__global__ void k_bias(const float* __restrict__ bq, const float* __restrict__ bk,
                       const float* __restrict__ bv, float* __restrict__ bqkv) {
  int i = blockIdx.x * 256 + threadIdx.x;          // < NQKV
  float v = (i < DMODEL) ? bq[i] : (i < DMODEL + NKV ? bk[i - DMODEL] : bv[i - DMODEL - NKV]);
  bqkv[i] = v;
}

// W: [K][N] fp32 row-major -> Wt: [N][K] bf16 row-major
__global__ void k_transpose_cast(const float* __restrict__ W, int N,
                                 u16_t* __restrict__ Wt, int K) {
  __shared__ float tile[64][65];
  int n0 = blockIdx.x * 64, k0 = blockIdx.y * 64;
  int t = threadIdx.x;
#pragma unroll
  for (int pass = 0; pass < 4; ++pass) {
    int slot = pass * 256 + t;
    int r = slot >> 4, c4 = (slot & 15) * 4;
    float4 v = *(const float4*)(W + (size_t)(k0 + r) * N + n0 + c4);
    tile[r][c4] = v.x; tile[r][c4 + 1] = v.y; tile[r][c4 + 2] = v.z; tile[r][c4 + 3] = v.w;
  }
  __syncthreads();
  int nr = t >> 2, seg = t & 3;
  alignas(16) u16_t o[16];
#pragma unroll
  for (int kk = 0; kk < 16; ++kk) o[kk] = f2bf(tile[seg * 16 + kk][nr]);
  u16_t* dst = Wt + (size_t)(n0 + nr) * K + k0 + seg * 16;
  ((int4*)dst)[0] = ((const int4*)o)[0];
  ((int4*)dst)[1] = ((const int4*)o)[1];
}

// ---------------- GEMM: C[M][N] = A[M][K](bf16) * Bt[N][K](bf16)^T + bias ----------
// 128x128 tile, BK=32, 256 threads (4 waves, 2x2), per-wave 64x64 (acc[4][4]).
// Round-12: register-pipelined regions (attn-R11 trick applied to GEMM):
//   region t: stage(t+2) issued first (full-region latency cover)
//             ds_read frags(t+1) -> NEXT reg set  (LDS pipe)
//             MFMA(t) on CURRENT reg set          (matrix pipe, independent)
//             __syncthreads()   [one barrier per region; full drain ledger --
//                                retires my reads (slot t&1 freed for stage t+3)
//                                and my stage (slot (t+2)&1 valid next region)]
// Reg sets ping-pong A/B via unroll-by-2 (static indexing, rule #20).
// Plain 2D grid (best L2/L3 locality, R9 lesson). Source-preswizzled chunks.
// EPI 0: fp32 out.  EPI 1: QKV epilogue (RoPE, Q pre-scaled, V transposed).

template <int EPI>
__global__ __launch_bounds__(256, 2) void k_gemm(
    const u16_t* __restrict__ A, const u16_t* __restrict__ Bt, const float* __restrict__ bias,
    float* __restrict__ Cout, u16_t* __restrict__ Qb, u16_t* __restrict__ Kb,
    u16_t* __restrict__ Vt, const float* __restrict__ cosT, const float* __restrict__ sinT,
    int M, int N, int K) {
  // u16: A slot0 [0,4096), A slot1 [4096,8192), B slot0 [8192,12288), B slot1 [12288,16384)
  __shared__ u16_t lds[16384];
  int tid = threadIdx.x;
  int wid = tid >> 6, lane = tid & 63;
  int l15 = lane & 15, l4 = lane >> 4;
  int wrow = wid >> 1, wcol = wid & 1;

  int m0 = blockIdx.y << 7, n0 = blockIdx.x << 7;

  f32x4 acc[4][4] = {};

  auto stage = [&](int t) {
    u16_t* Al = lds + (t & 1) * 4096;
    u16_t* Bl = lds + 8192 + (t & 1) * 4096;
    int kbase = t * 32;
#pragma unroll
    for (int ss = 0; ss < 2; ++ss) {
      int slot = tid + ss * 256;
      int row = slot >> 2, c = slot & 3;
      int cs = c ^ (row & 3);
      __builtin_amdgcn_global_load_lds(
          (const __attribute__((address_space(1))) u32_t*)(A + (size_t)(m0 + row) * K + kbase + cs * 8),
          (__attribute__((address_space(3))) u32_t*)(Al + slot * 8), 16, 0, 0);
      __builtin_amdgcn_global_load_lds(
          (const __attribute__((address_space(1))) u32_t*)(Bt + (size_t)(n0 + row) * K + kbase + cs * 8),
          (__attribute__((address_space(3))) u32_t*)(Bl + slot * 8), 16, 0, 0);
    }
  };

  auto rdfrags = [&](int t, bf16x8 (&af)[4], bf16x8 (&bfr)[4]) {
    const u16_t* Ac = lds + (t & 1) * 4096;
    const u16_t* Bc = lds + 8192 + (t & 1) * 4096;
    int chunk = l4 ^ (l15 & 3);
#pragma unroll
    for (int i = 0; i < 4; ++i)
      af[i] = *(const bf16x8*)(Ac + (wrow * 64 + i * 16 + l15) * 32 + chunk * 8);
#pragma unroll
    for (int j = 0; j < 4; ++j)
      bfr[j] = *(const bf16x8*)(Bc + (wcol * 64 + j * 16 + l15) * 32 + chunk * 8);
  };

  bf16x8 afA[4], bfA[4], afB[4], bfB[4];

  auto mfma16 = [&](bf16x8 (&af)[4], bf16x8 (&bfr)[4]) {
    __builtin_amdgcn_s_setprio(1);
#pragma unroll
    for (int i = 0; i < 4; ++i)
#pragma unroll
      for (int j = 0; j < 4; ++j)
        acc[i][j] = __builtin_amdgcn_mfma_f32_16x16x32_bf16(af[i], bfr[j], acc[i][j], 0, 0, 0);
    __builtin_amdgcn_s_setprio(0);
  };

  const int NT = K >> 5;   // 64

  stage(0);
  stage(1);
  __syncthreads();                 // stage(0) and stage(1) landed (prologue-only full drain)
  rdfrags(0, afA, bfA);
  __syncthreads();                 // all waves' frags(0) in regs -> slot0 free

  // region t: stage(t+2); rdfrags(t+1) -> NXT; MFMA(t) on CUR; __syncthreads
  for (int p = 0; p < NT / 2 - 1; ++p) {     // p = 0..30 -> t = 0..61
    int t0 = 2 * p;
    if (t0 + 2 < NT) stage(t0 + 2);
    rdfrags(t0 + 1, afB, bfB);
    mfma16(afA, bfA);
    __syncthreads();
    int t1 = 2 * p + 1;
    if (t1 + 2 < NT) stage(t1 + 2);
    rdfrags(t1 + 1, afA, bfA);
    mfma16(afB, bfB);
    __syncthreads();
  }
  // t = NT-2 (62): no stage; read last tile; compute 62
  rdfrags(NT - 1, afB, bfB);
  mfma16(afA, bfA);
  __syncthreads();
  // t = NT-1 (63): compute only
  mfma16(afB, bfB);

  if (EPI == 0) {
#pragma unroll
    for (int j = 0; j < 4; ++j) {
      int n = n0 + wcol * 64 + j * 16 + l15;
      float bs = bias[n];
#pragma unroll
      for (int i = 0; i < 4; ++i) {
        int mbase = m0 + wrow * 64 + i * 16 + l4 * 4;
#pragma unroll
        for (int r = 0; r < 4; ++r)
          Cout[(size_t)(mbase + r) * N + n] = acc[i][j][r] + bs;
      }
    }
  } else {
    bool isV = (n0 >= DMODEL + NKV);
    bool isK = (n0 >= DMODEL) && !isV;
#pragma unroll
    for (int j = 0; j < 4; ++j) {
      int n = n0 + wcol * 64 + j * 16 + l15;
      float bs = bias[n];
      int d = n & (HDIM - 1);
      int p = d >> 1;
      bool evn = !(d & 1);
#pragma unroll
      for (int i = 0; i < 4; ++i) {
        int mbase = m0 + wrow * 64 + i * 16 + l4 * 4;
        if (isV) {
          int g = (n - DMODEL - NKV) >> 7;
          int b = mbase >> 11, s0 = mbase & (SEQ - 1);
          u16_t o[4];
#pragma unroll
          for (int r = 0; r < 4; ++r) o[r] = f2bf(acc[i][j][r] + bs);
          uint2 pk;
          pk.x = (u32_t)o[0] | ((u32_t)o[1] << 16);
          pk.y = (u32_t)o[2] | ((u32_t)o[3] << 16);
          *(uint2*)(Vt + ((size_t)(b * NGRP + g) * HDIM + d) * SEQ + s0) = pk;
        } else {
#pragma unroll
          for (int r = 0; r < 4; ++r) {
            int m = mbase + r;
            int b = m >> 11, s = m & (SEQ - 1);
            float val = acc[i][j][r] + bs;
            float pv = __shfl_xor(val, 1);
            float c = cosT[s * (HDIM / 2) + p];
            float sn = sinT[s * (HDIM / 2) + p];
            float outv = evn ? (val * c - pv * sn) : (pv * sn + val * c);
            if (isK) {
              int g = (n - DMODEL) >> 7;
              Kb[((size_t)(b * NGRP + g) * SEQ + s) * HDIM + d] = f2bf(outv);
            } else {
              int h = n >> 7;
              Qb[((size_t)(b * NHEAD + h) * SEQ + s) * HDIM + d] = f2bf(outv * QSCALE_LOG2E);
            }
          }
        }
      }
    }
  }
}

// ---------------- flash attention (unchanged from round 11) ----------------

__global__ __launch_bounds__(256, 2) void k_attn(
    const u16_t* __restrict__ Qb, const u16_t* __restrict__ Kb, const u16_t* __restrict__ Vt,
    u16_t* __restrict__ attn_out) {
  __shared__ u16_t lds[32768];   // K0,K1,V0,V1: 8192 u16 each

  int tid = threadIdx.x, wid = tid >> 6, lane = tid & 63;
  int l15 = lane & 15, l4 = lane >> 4;
  int bh = blockIdx.y;
  int b = bh >> 4, h = bh & 15, g = h >> 2;
  int q0 = blockIdx.x * 128;
  const u16_t* Qhead = Qb + (size_t)(b * NHEAD + h) * SEQ * HDIM;
  const u16_t* Khead = Kb + (size_t)(b * NGRP + g) * SEQ * HDIM;
  const u16_t* Vhead = Vt + (size_t)(b * NGRP + g) * HDIM * SEQ;

  bf16x8 qfa[4], qfb[4];
#pragma unroll
  for (int kc = 0; kc < 4; ++kc) {
    qfa[kc] = *(const bf16x8*)(Qhead + (size_t)(q0 + wid * 32 + l15) * HDIM + kc * 32 + l4 * 8);
    qfb[kc] = *(const bf16x8*)(Qhead + (size_t)(q0 + wid * 32 + 16 + l15) * HDIM + kc * 32 + l4 * 8);
  }

  f32x4 oa[8] = {}, ob[8] = {};
  float la = 0.f, lb = 0.f;

  auto stage = [&](int kv0, int bufIdx) {
    u16_t* Kl = lds + bufIdx * 8192;
    u16_t* Vl = lds + 16384 + bufIdx * 8192;
#pragma unroll
    for (int ss = 0; ss < 4; ++ss) {
      int slot = tid + ss * 256;
      int rK = slot >> 4;
      int cK = (slot & 15) ^ ((rK & 3) | (((rK >> 3) & 1) << 2));
      __builtin_amdgcn_global_load_lds(
          (const __attribute__((address_space(1))) u32_t*)(Khead + (size_t)(kv0 + rK) * HDIM + cK * 8),
          (__attribute__((address_space(3))) u32_t*)(Kl + slot * 8), 16, 0, 0);
      int rV = slot >> 3, cV = (slot & 7) ^ (rV & 7);
      __builtin_amdgcn_global_load_lds(
          (const __attribute__((address_space(1))) u32_t*)(Vhead + (size_t)rV * SEQ + kv0 + cV * 8),
          (__attribute__((address_space(3))) u32_t*)(Vl + slot * 8), 16, 0, 0);
    }
  };

  auto qk = [&](int bufIdx, f32x4 (&Sa)[4], f32x4 (&Sb)[4]) {
    const u16_t* Kcur = lds + bufIdx * 8192;
#pragma unroll
    for (int kc = 0; kc < 4; ++kc) {
#pragma unroll
      for (int kvb = 0; kvb < 4; ++kvb) {
        int row = (l15 >> 2) * 8 + ((kvb & 1) << 2) + (l15 & 3) + ((kvb >> 1) << 5);
        int chunk = ((kc << 2) + l4) ^ (l15 & 7);
        bf16x8 kf = *(const bf16x8*)(Kcur + row * 128 + chunk * 8);
        Sa[kvb] = __builtin_amdgcn_mfma_f32_16x16x32_bf16(kf, qfa[kc], Sa[kvb], 0, 0, 0);
        Sb[kvb] = __builtin_amdgcn_mfma_f32_16x16x32_bf16(kf, qfb[kc], Sb[kvb], 0, 0, 0);
      }
    }
  };

  auto expand = [&](f32x4 (&Sa)[4], f32x4 (&Sb)[4], bf16x8 (&pfa)[2], bf16x8 (&pfb)[2]) {
    bf16x4 pa[4], pb[4];
#pragma unroll
    for (int kvb = 0; kvb < 4; ++kvb) {
#pragma unroll
      for (int r = 0; r < 4; ++r) {
        float ea = __builtin_amdgcn_exp2f(Sa[kvb][r]);
        float eb = __builtin_amdgcn_exp2f(Sb[kvb][r]);
        la += ea; lb += eb;
        pa[kvb][r] = (__bf16)ea;
        pb[kvb][r] = (__bf16)eb;
      }
    }
#pragma unroll
    for (int kc2 = 0; kc2 < 2; ++kc2) {
      uint2 alo = __builtin_bit_cast(uint2, pa[kc2 * 2]);
      uint2 ahi = __builtin_bit_cast(uint2, pa[kc2 * 2 + 1]);
      uint4 wa; wa.x = alo.x; wa.y = alo.y; wa.z = ahi.x; wa.w = ahi.y;
      pfa[kc2] = __builtin_bit_cast(bf16x8, wa);
      uint2 blo = __builtin_bit_cast(uint2, pb[kc2 * 2]);
      uint2 bhi = __builtin_bit_cast(uint2, pb[kc2 * 2 + 1]);
      uint4 wb; wb.x = blo.x; wb.y = blo.y; wb.z = bhi.x; wb.w = bhi.y;
      pfb[kc2] = __builtin_bit_cast(bf16x8, wb);
    }
  };

  auto pv = [&](int bufIdx, bf16x8 (&pfa)[2], bf16x8 (&pfb)[2]) {
    const u16_t* Vcur = lds + 16384 + bufIdx * 8192;
#pragma unroll
    for (int kc2 = 0; kc2 < 2; ++kc2) {
#pragma unroll
      for (int dcb = 0; dcb < 8; ++dcb) {
        int chunk = ((kc2 << 2) + l4) ^ (l15 & 7);
        bf16x8 vf = *(const bf16x8*)(Vcur + (dcb * 16 + l15) * 64 + chunk * 8);
        oa[dcb] = __builtin_amdgcn_mfma_f32_16x16x32_bf16(vf, pfa[kc2], oa[dcb], 0, 0, 0);
        ob[dcb] = __builtin_amdgcn_mfma_f32_16x16x32_bf16(vf, pfb[kc2], ob[dcb], 0, 0, 0);
      }
    }
  };

  auto step = [&](int t, f32x4 (&Ia)[4], f32x4 (&Ib)[4], f32x4 (&Oa)[4], f32x4 (&Ob)[4]) {
    bf16x8 pfa[2], pfb[2];
    expand(Ia, Ib, pfa, pfb);
    asm volatile("s_waitcnt vmcnt(0)" ::: "memory");
    __builtin_amdgcn_s_barrier();
    __builtin_amdgcn_sched_barrier(0);
#pragma unroll
    for (int z = 0; z < 4; ++z)
#pragma unroll
      for (int r = 0; r < 4; ++r) { Oa[z][r] = 0.f; Ob[z][r] = 0.f; }
    __builtin_amdgcn_s_setprio(1);
    pv(t & 1, pfa, pfb);
    qk((t + 1) & 1, Oa, Ob);
    __builtin_amdgcn_s_setprio(0);
    __builtin_amdgcn_sched_barrier(0);
    __builtin_amdgcn_s_barrier();
    __builtin_amdgcn_sched_barrier(0);
    if (t + 2 < SEQ / 64) stage((t + 2) * 64, t & 1);
  };

  f32x4 sA[4] = {}, sB[4] = {}, tA[4], tB[4];

  stage(0, 0);
  stage(64, 1);
  asm volatile("s_waitcnt vmcnt(8)" ::: "memory");
  __builtin_amdgcn_s_barrier();
  __builtin_amdgcn_sched_barrier(0);
  qk(0, sA, sB);

  for (int p = 0; p < 15; ++p) {
    step(2 * p, sA, sB, tA, tB);
    step(2 * p + 1, tA, tB, sA, sB);
  }
  step(30, sA, sB, tA, tB);
  {
    bf16x8 pfa[2], pfb[2];
    expand(tA, tB, pfa, pfb);
    pv(1, pfa, pfb);
  }

  la += __shfl_xor(la, 16); la += __shfl_xor(la, 32);
  lb += __shfl_xor(lb, 16); lb += __shfl_xor(lb, 32);
  float inva = 1.0f / la, invb = 1.0f / lb;

#pragma unroll
  for (int half = 0; half < 2; ++half) {
    u16_t* Owave = lds + half * 8704 + wid * 2176;
    const f32x4* oacc = half ? ob : oa;
    float inv = half ? invb : inva;
#pragma unroll
    for (int dcb = 0; dcb < 8; ++dcb) {
      bf16x4 ov;
#pragma unroll
      for (int r = 0; r < 4; ++r) ov[r] = (__bf16)(oacc[dcb][r] * inv);
      *(uint2*)(Owave + l15 * 136 + dcb * 16 + l4 * 4) = __builtin_bit_cast(uint2, ov);
    }
#pragma unroll
    for (int pass = 0; pass < 4; ++pass) {
      int rowq = pass * 4 + l4;
      int4 v = *(const int4*)(Owave + rowq * 136 + l15 * 8);
      int s = q0 + wid * 32 + half * 16 + rowq;
      *(int4*)(attn_out + ((size_t)(b * SEQ + s)) * DMODEL + h * HDIM + l15 * 8) = v;
    }
  }
}

// ---------------- launcher ----------------

extern "C" void kernel_launch(void* const* d_in, const int* in_sizes, int n_in,
                              void* d_out, int out_size, void* d_ws, size_t ws_size,
                              hipStream_t stream) {
  (void)in_sizes; (void)n_in; (void)out_size; (void)ws_size;
  const float* x  = (const float*)d_in[0];
  const float* rf = (const float*)d_in[1];
  const float* Wq = (const float*)d_in[2];
  const float* bq = (const float*)d_in[3];
  const float* Wk = (const float*)d_in[4];
  const float* bk = (const float*)d_in[5];
  const float* Wv = (const float*)d_in[6];
  const float* bv = (const float*)d_in[7];
  const float* Wo = (const float*)d_in[8];
  const float* bo = (const float*)d_in[9];
  float* out = (float*)d_out;

  char* ws = (char*)d_ws;
  u16_t* xb    = (u16_t*)ws;  ws += (size_t)MROWS * DMODEL * 2;
  u16_t* Wqkvt = (u16_t*)ws;  ws += (size_t)NQKV * DMODEL * 2;
  u16_t* Wot   = (u16_t*)ws;  ws += (size_t)DMODEL * DMODEL * 2;
  float* bqkv  = (float*)ws;  ws += (size_t)NQKV * 4;
  float* cosT  = (float*)ws;  ws += (size_t)SEQ * (HDIM / 2) * 4;
  float* sinT  = (float*)ws;  ws += (size_t)SEQ * (HDIM / 2) * 4;
  u16_t* Qb    = (u16_t*)ws;  ws += (size_t)NB * NHEAD * SEQ * HDIM * 2;
  u16_t* Kb    = (u16_t*)ws;  ws += (size_t)NB * NGRP * SEQ * HDIM * 2;
  u16_t* Vt    = (u16_t*)ws;  ws += (size_t)NB * NGRP * HDIM * SEQ * 2;
  u16_t* attn  = xb;  // alias: xb dead after GEMM1 (strict stream ordering)

  k_cast_x<<<MROWS * DMODEL / 1024, 256, 0, stream>>>(x, xb);
  k_tables<<<SEQ * (HDIM / 2) / 256, 256, 0, stream>>>(rf, cosT, sinT);
  k_bias<<<NQKV / 256, 256, 0, stream>>>(bq, bk, bv, bqkv);

  dim3 tgq(DMODEL / 64, DMODEL / 64);
  dim3 tgk(NKV / 64, DMODEL / 64);
  k_transpose_cast<<<tgq, 256, 0, stream>>>(Wq, DMODEL, Wqkvt, DMODEL);
  k_transpose_cast<<<tgk, 256, 0, stream>>>(Wk, NKV, Wqkvt + (size_t)DMODEL * DMODEL, DMODEL);
  k_transpose_cast<<<tgk, 256, 0, stream>>>(Wv, NKV, Wqkvt + (size_t)(DMODEL + NKV) * DMODEL, DMODEL);
  k_transpose_cast<<<tgq, 256, 0, stream>>>(Wo, DMODEL, Wot, DMODEL);

  // GEMM1: 4096 x 3072 x 2048
  k_gemm<1><<<dim3(NQKV / 128, MROWS / 128), 256, 0, stream>>>(
      xb, Wqkvt, bqkv, nullptr, Qb, Kb, Vt, cosT, sinT, MROWS, NQKV, DMODEL);

  dim3 ga(SEQ / 128, NB * NHEAD);
  k_attn<<<ga, 256, 0, stream>>>(Qb, Kb, Vt, attn);

  // GEMM2: 4096 x 2048 x 2048
  k_gemm<0><<<dim3(DMODEL / 128, MROWS / 128), 256, 0, stream>>>(
      attn, Wot, bo, out, nullptr, nullptr, nullptr, nullptr, nullptr, MROWS, DMODEL, DMODEL);
}